// Round 3
// baseline (425.328 us; speedup 1.0000x reference)
//
#include <hip/hip_runtime.h>

#define BB 2
#define NN 32768
#define EN 32768
#define NBLK 256

typedef unsigned int u32;
typedef __attribute__((ext_vector_type(8)))  short bf16x8;
typedef __attribute__((ext_vector_type(2)))  float f32x2;
typedef __attribute__((ext_vector_type(16))) float f32x16;

union U4 { uint4 u; bf16x8 h; };

// Single-instruction bf16 pack (no gfx950 builtin; RNE).
__device__ __forceinline__ u32 pk2(float lo, float hi) {
    u32 r;
    asm("v_cvt_pk_bf16_f32 %0, %1, %2" : "=v"(r) : "v"(lo), "v"(hi));
    return r;
}

// lane<->lane^32 sum via permlane32_swap (VALU, no LDS latency).
__device__ __forceinline__ float xor32_sum(float x) {
    float y = x;
    asm("v_permlane32_swap_b32 %0, %1" : "+v"(x), "+v"(y));
    return x + y;
}

__device__ __forceinline__ f32x16 MF32(bf16x8 a, bf16x8 b, f32x16 c) {
    return __builtin_amdgcn_mfma_f32_32x32x16_bf16(a, b, c, 0, 0, 0);
}

// ---------------------------------------------------------------------------
// 32x32 MFMA engine (round-1 proven). Lane (e = lane&31, h = lane>>5).
// C/D: col = e, row(r,h) = (r&3) + 8*(r>>2) + 4h.
// pi: f(t,h,j) = 16t + 4h + (j&3) + 8*(j>>2) -> layer-to-layer pure registers.
// ---------------------------------------------------------------------------
template<bool LN>
__device__ __forceinline__ void transform32(f32x16 D, bf16x8& B0, bf16x8& B1)
{
    f32x2 p0 = {D[0],D[1]},  p1 = {D[2],D[3]},  p2 = {D[4],D[5]},  p3 = {D[6],D[7]};
    f32x2 p4 = {D[8],D[9]},  p5 = {D[10],D[11]},p6 = {D[12],D[13]},p7 = {D[14],D[15]};
    const f32x2 zz = {0.f, 0.f};
    p0 = __builtin_elementwise_max(p0, zz); p1 = __builtin_elementwise_max(p1, zz);
    p2 = __builtin_elementwise_max(p2, zz); p3 = __builtin_elementwise_max(p3, zz);
    p4 = __builtin_elementwise_max(p4, zz); p5 = __builtin_elementwise_max(p5, zz);
    p6 = __builtin_elementwise_max(p6, zz); p7 = __builtin_elementwise_max(p7, zz);
    if (LN) {
        f32x2 sv = ((p0+p1)+(p2+p3)) + ((p4+p5)+(p6+p7));
        f32x2 ta = __builtin_elementwise_fma(p0,p0,
                   __builtin_elementwise_fma(p1,p1,
                   __builtin_elementwise_fma(p2,p2, p3*p3)));
        f32x2 tb = __builtin_elementwise_fma(p4,p4,
                   __builtin_elementwise_fma(p5,p5,
                   __builtin_elementwise_fma(p6,p6, p7*p7)));
        f32x2 tv = ta + tb;
        float s = xor32_sum(sv.x + sv.y);
        float t = xor32_sum(tv.x + tv.y);
        float mu  = s * (1.f/32.f);
        float var = fmaf(-mu, mu, t * (1.f/32.f));
        float rs  = rsqrtf(var + 1e-5f);
        float nt  = -mu * rs;
        f32x2 rs2 = {rs, rs}, nt2 = {nt, nt};
        p0 = __builtin_elementwise_fma(p0, rs2, nt2);
        p1 = __builtin_elementwise_fma(p1, rs2, nt2);
        p2 = __builtin_elementwise_fma(p2, rs2, nt2);
        p3 = __builtin_elementwise_fma(p3, rs2, nt2);
        p4 = __builtin_elementwise_fma(p4, rs2, nt2);
        p5 = __builtin_elementwise_fma(p5, rs2, nt2);
        p6 = __builtin_elementwise_fma(p6, rs2, nt2);
        p7 = __builtin_elementwise_fma(p7, rs2, nt2);
    }
    U4 c;
    c.u.x = pk2(p0.x,p0.y); c.u.y = pk2(p1.x,p1.y);
    c.u.z = pk2(p2.x,p2.y); c.u.w = pk2(p3.x,p3.y);
    B0 = c.h;
    c.u.x = pk2(p4.x,p4.y); c.u.y = pk2(p5.x,p5.y);
    c.u.z = pk2(p6.x,p6.y); c.u.w = pk2(p7.x,p7.y);
    B1 = c.h;
}

// Direct aligned f32x16 LDS load (WB 64B-aligned, base multiples of 32 floats,
// h*16 floats = 64B) -> 4x ds_read_b128 straight into the C registers, no
// per-element assembly movs.
__device__ __forceinline__ f32x16 load_biasC(const float* WB, int base, int h) {
    return *(const f32x16*)(WB + base + h*16);
}

// WL (dwords): [Bin NT*256][Bh 32*512][Bo 512]
template<int NT, bool LN>
__device__ __forceinline__ f32x16 mlp32(const bf16x8* bIn,
    const u32* WL, const float* WB, int lane, int h)
{
    constexpr int HB = NT*256;
    constexpr int BO = HB + 16384;
    U4 c;
    f32x16 D = load_biasC(WB, 0, h);
    #pragma unroll
    for (int t = 0; t < NT; ++t) {
        c.u = *(const uint4*)(WL + t*256 + lane*4);
        D = MF32(c.h, bIn[t], D);
    }
    c.u = *(const uint4*)(WL + HB + lane*4);        bf16x8 w0 = c.h;
    c.u = *(const uint4*)(WL + HB + 256 + lane*4);  bf16x8 w1 = c.h;
    c.u = *(const uint4*)(WL + HB + 512 + lane*4);  bf16x8 x0 = c.h;
    c.u = *(const uint4*)(WL + HB + 768 + lane*4);  bf16x8 x1 = c.h;
    f32x16 pb = load_biasC(WB, 32, h);
    bf16x8 B0, B1;
    transform32<LN>(D, B0, B1);
    #pragma unroll 4
    for (int l = 0; l < 32; ++l) {
        const int lp = (l+2 < 32) ? l+2 : 31;
        c.u = *(const uint4*)(WL + HB + lp*512 + lane*4);       bf16x8 nw0 = c.h;
        c.u = *(const uint4*)(WL + HB + lp*512 + 256 + lane*4); bf16x8 nw1 = c.h;
        const int lb_ = (l+1 < 32) ? l+1 : 31;
        f32x16 nb = load_biasC(WB, 32 + lb_*32, h);
        f32x16 E = MF32(w0, B0, pb);
        E = MF32(w1, B1, E);
        transform32<LN>(E, B0, B1);
        w0 = x0; w1 = x1; x0 = nw0; x1 = nw1; pb = nb;
    }
    c.u = *(const uint4*)(WL + BO + lane*4);        bf16x8 o0 = c.h;
    c.u = *(const uint4*)(WL + BO + 256 + lane*4);  bf16x8 o1 = c.h;
    f32x16 Co = load_biasC(WB, 1056, h);
    f32x16 O = MF32(o0, B0, Co);
    O = MF32(o1, B1, O);
    return O;
}

// ---------------------------------------------------------------------------
// Staging pieces (DMA has no sync; callers control barriers).
// ---------------------------------------------------------------------------
__device__ __forceinline__ void stage_dma(u32* WL, const u32* __restrict__ Wp,
                                          int wtot, int tid)
{
    const int lane = tid & 63;
    for (int C = (tid >> 6)*256; C < wtot; C += 8*256)
        __builtin_amdgcn_global_load_lds(
            (const __attribute__((address_space(1))) u32*)(Wp + C + lane*4),
            (__attribute__((address_space(3))) u32*)(WL + C), 16, 0, 0);
}

// Biases permuted to C-operand layout WB[region + h*16 + r] = b[(r&3)+8*(r>>2)+4h].
// WB (floats): [0..32) bin | [32..1056) hidden | [1056..1088) out
__device__ __forceinline__ void stage_bias(float* WB,
    const float* __restrict__ bin, const float* __restrict__ bhid,
    const float* __restrict__ bo, int nbo, int tid)
{
    for (int i = tid; i < 1088; i += 512) {
        float v;
        if (i < 32) {
            int w = i, hh = w>>4, r = w&15;
            int f = (r&3) + 8*(r>>2) + 4*hh;
            v = bin[f];
        } else if (i < 1056) {
            int l = (i-32)>>5, w = (i-32)&31, hh = w>>4, r = w&15;
            int f = (r&3) + 8*(r>>2) + 4*hh;
            v = bhid[l*32 + f];
        } else {
            int w = i-1056, hh = w>>4, r = w&15;
            int f = (r&3) + 8*(r>>2) + 4*hh;
            v = (f < nbo) ? bo[f] : 0.f;
        }
        WB[i] = v;
    }
}

__device__ __forceinline__ void stage_weights32(
    u32* WL, float* WB, const u32* __restrict__ Wp,
    const float* __restrict__ bin, const float* __restrict__ bhid,
    const float* __restrict__ bo, int wtot, int nbo, int tid)
{
    stage_dma(WL, Wp, wtot, tid);
    stage_bias(WB, bin, bhid, bo, nbo, tid);
    __syncthreads();
}

// Device-scope spin barrier. All 256 blocks are co-resident (155KB LDS ->
// 1 block/CU, grid == CU count). Counters zeroed by the captured memset
// every launch, so monotone counters are safe across graph replays.
__device__ __forceinline__ void gridbar(u32* bar)
{
    __threadfence();          // per-thread release (drains vmcnt incl. DMA)
    __syncthreads();
    if (threadIdx.x == 0) {
        u32 prev = __hip_atomic_fetch_add(bar, 1u, __ATOMIC_ACQ_REL,
                                          __HIP_MEMORY_SCOPE_AGENT);
        if (prev + 1u < NBLK) {
            u32 v;
            do {
                __builtin_amdgcn_s_sleep(2);
                v = __hip_atomic_load(bar, __ATOMIC_ACQUIRE,
                                      __HIP_MEMORY_SCOPE_AGENT);
            } while (v < NBLK);
        }
    }
    __syncthreads();
}

// ---------------------------------------------------------------------------
// prep: weight packing to 32x32 pi layout + LN fold (round-1 verbatim).
// ---------------------------------------------------------------------------
__device__ __forceinline__ void pack_body32(
    const float* __restrict__ Win, const float* __restrict__ Wh,
    const float* __restrict__ Wout, const float* __restrict__ lng,
    u32* __restrict__ dst, int din, int dout, int NT, int lb, int tid)
{
    int t = lb * 256 + tid;
    int binW = NT * 256;
    int tot = binW + 16384 + 512;
    if (t >= tot) return;
    float lo, hi;
    if (t < binW) {
        int tt = t>>8, rem = t&255, ln_ = rem>>2, d = rem&3;
        int hh = ln_>>5, m = ln_&31;
        int f0 = 16*tt + 4*hh + 2*(d&1) + 8*(d>>1);
        lo = (f0   < din) ? Win[f0*32 + m]     : 0.f;
        hi = (f0+1 < din) ? Win[(f0+1)*32 + m] : 0.f;
    } else if (t < binW + 16384) {
        int u = t - binW, l = u>>9, v = u&511;
        int tt = v>>8, rem = v&255, ln_ = rem>>2, d = rem&3;
        int hh = ln_>>5, m = ln_&31;
        int f0 = 16*tt + 4*hh + 2*(d&1) + 8*(d>>1);
        lo = Wh[l*1024 + f0*32 + m];
        hi = Wh[l*1024 + (f0+1)*32 + m];
        if (lng) { lo *= lng[l*32 + f0]; hi *= lng[l*32 + f0 + 1]; }
    } else {
        int u = t - binW - 16384;
        int tt = u>>8, rem = u&255, ln_ = rem>>2, d = rem&3;
        int hh = ln_>>5, m = ln_&31;
        int f0 = 16*tt + 4*hh + 2*(d&1) + 8*(d>>1);
        lo = (m < dout) ? Wout[f0*dout + m]     : 0.f;
        hi = (m < dout) ? Wout[(f0+1)*dout + m] : 0.f;
        if (lng) { lo *= lng[1024 + f0]; hi *= lng[1024 + f0 + 1]; }
    }
    dst[t] = pk2(lo, hi);
}

__device__ __forceinline__ void fold_body(
    const float* __restrict__ Wh,   const float* __restrict__ bh,
    const float* __restrict__ Wout, const float* __restrict__ bout,
    const float* __restrict__ lnb,  float* __restrict__ fb, int lb, int tid)
{
    int j = lb * 256 + tid;
    if (j < 1024) {
        int l = j >> 5, jj = j & 31;
        float acc = bh[j];
        #pragma unroll
        for (int k = 0; k < 32; ++k)
            acc = fmaf(lnb[l*32 + k], Wh[l*1024 + k*32 + jj], acc);
        fb[j] = acc;
    } else if (j < 1024 + 16) {
        int jj = j - 1024;
        float acc = bout[jj];
        #pragma unroll
        for (int k = 0; k < 32; ++k)
            acc = fmaf(lnb[1024 + k], Wout[k*16 + jj], acc);
        fb[j] = acc;
    }
}

__global__ __launch_bounds__(256) void prep_kernel(
    const float* ne_Win, const float* ne_Wh, const float* ne_Wout,
    const float* ed_Win, const float* ed_Wh, const float* ed_Wout,
    const float* pe_Win, const float* pe_Wh, const float* pe_Wout,
    const float* pe_lng, const float* pe_lnb, const float* pe_bh, const float* pe_bout,
    const float* pv_Win, const float* pv_Wh, const float* pv_Wout,
    const float* pv_lng, const float* pv_lnb, const float* pv_bh, const float* pv_bout,
    const float* de_Win, const float* de_Wh, const float* de_Wout,
    u32* Wne, u32* Wed, u32* Wpe, u32* Wpv, u32* Wde,
    float* Fpe, float* Fpv)
{
    int bx = blockIdx.x, tid = threadIdx.x;
    if      (bx < 67)  pack_body32(ne_Win, ne_Wh, ne_Wout, nullptr, Wne,  7, 16, 1, bx,       tid);
    else if (bx < 134) pack_body32(ed_Win, ed_Wh, ed_Wout, nullptr, Wed,  5, 16, 1, bx - 67,  tid);
    else if (bx < 204) pack_body32(pe_Win, pe_Wh, pe_Wout, pe_lng,  Wpe, 49, 16, 4, bx - 134, tid);
    else if (bx < 273) pack_body32(pv_Win, pv_Wh, pv_Wout, pv_lng,  Wpv, 33, 16, 3, bx - 204, tid);
    else if (bx < 340) pack_body32(de_Win, de_Wh, de_Wout, nullptr, Wde, 16,  3, 1, bx - 273, tid);
    else if (bx < 345) fold_body(pe_Wh, pe_bh, pe_Wout, pe_bout, pe_lnb, Fpe, bx - 340, tid);
    else               fold_body(pv_Wh, pv_bh, pv_Wout, pv_bout, pv_lnb, Fpv, bx - 345, tid);
}

__device__ __forceinline__ bf16x8 stage_chunk(const float* __restrict__ arr,
                                              size_t e, int h)
{
    const int off = h*4;
    float4 a = *(const float4*)(arr + e*16 + off);
    float4 b = *(const float4*)(arr + e*16 + off + 8);
    U4 c;
    c.u.x = pk2(a.x, a.y); c.u.y = pk2(a.z, a.w);
    c.u.z = pk2(b.x, b.y); c.u.w = pk2(b.z, b.w);
    return c.h;
}

#define WAVE_SETUP \
    const int lane = threadIdx.x & 63; \
    const int wid  = threadIdx.x >> 6; \
    const int el = lane & 31, h = lane >> 5;

// ---------------------------------------------------------------------------
// encode: round-1 verbatim. 512 blocks (2/CU -> 4 chains/SIMD).
// ---------------------------------------------------------------------------
__global__ __launch_bounds__(512, 4) void encode_kernel(
    const float* __restrict__ nodes, const float* __restrict__ edges,
    const float* __restrict__ gvec,
    const int* __restrict__ senders, const int* __restrict__ receivers,
    const u32* __restrict__ Wne, const float* __restrict__ ne_bin,
    const float* __restrict__ ne_bh, const float* __restrict__ ne_bout,
    const u32* __restrict__ Wed, const float* __restrict__ ed_bin,
    const float* __restrict__ ed_bh, const float* __restrict__ ed_bout,
    float* __restrict__ ve, float* __restrict__ ee)
{
    __shared__ __align__(16) u32 SL[17152 + 1088];
    u32* WL = SL;
    float* WB = (float*)(SL + 17152);
    WAVE_SETUP
    const bool edge_stage = blockIdx.x >= 256;
    stage_weights32(WL, WB,
                    edge_stage ? Wed : Wne,
                    edge_stage ? ed_bin : ne_bin,
                    edge_stage ? ed_bh : ne_bh,
                    edge_stage ? ed_bout : ne_bout,
                    17152, 16, threadIdx.x);
    const int lb = edge_stage ? (blockIdx.x - 256) : blockIdx.x;
    const int e = (lb*8 + wid)*32 + el;
    const int b = e >> 15;
    bf16x8 a0;
    {
        uint4 w; w.x = 0u; w.y = 0u; w.z = 0u; w.w = 0u;
        if (!edge_stage) {
            if (h == 0) {
                float2 v01 = *(const float2*)(nodes + (size_t)e*6);
                float2 v23 = *(const float2*)(nodes + (size_t)e*6 + 2);
                w.x = pk2(v01.x, v01.y); w.y = pk2(v23.x, v23.y);
            } else {
                float2 v45 = *(const float2*)(nodes + (size_t)e*6 + 4);
                w.x = pk2(v45.x, v45.y); w.y = pk2(gvec[b], 0.f);
            }
        } else {
            int s = senders[e], r = receivers[e];
            const float* ps = nodes + ((size_t)b*NN + s)*6;
            const float* pr = nodes + ((size_t)b*NN + r)*6;
            float2 s01 = *(const float2*)ps; float s2v = ps[2];
            float2 r01 = *(const float2*)pr; float r2v = pr[2];
            float r0 = s01.x - r01.x, r1 = s01.y - r01.y, r2 = s2v - r2v;
            if (h == 0) {
                w.x = pk2(edges[e], r0); w.y = pk2(r1, r2);
            } else {
                w.x = pk2(sqrtf(r0*r0 + r1*r1 + r2*r2), 0.f);
            }
        }
        U4 c; c.u = w; a0 = c.h;
    }
    float* dst = edge_stage ? ee : ve;
    f32x16 O = mlp32<1, false>(&a0, WL, WB, lane, h);
    float4 s1, s2;
    s1.x = fmaxf(O[0], 0.f); s1.y = fmaxf(O[1], 0.f);
    s1.z = fmaxf(O[2], 0.f); s1.w = fmaxf(O[3], 0.f);
    s2.x = fmaxf(O[4], 0.f); s2.y = fmaxf(O[5], 0.f);
    s2.z = fmaxf(O[6], 0.f); s2.w = fmaxf(O[7], 0.f);
    *(float4*)(dst + (size_t)e*16 + h*4)     = s1;
    *(float4*)(dst + (size_t)e*16 + h*4 + 8) = s2;
}

// ---------------------------------------------------------------------------
// Phase bodies for the fused kernel.
// ---------------------------------------------------------------------------
__device__ __forceinline__ void eu_phase(
    const float* __restrict__ gvec,
    const int* __restrict__ senders, const int* __restrict__ receivers,
    const float* __restrict__ ve, float* __restrict__ ee, float* __restrict__ agg,
    const u32* __restrict__ A, const float* __restrict__ WB, float* X,
    int lane, int wid, int el, int h)
{
    const int e0 = (blockIdx.x*8 + wid)*32;
    const int e  = e0 + el;
    const int b  = e >> 15;
    const int s  = senders[e], r_ = receivers[e];
    bf16x8 a[4];
    a[0] = stage_chunk(ee, (size_t)e, h);
    a[1] = stage_chunk(ve, (size_t)b*NN + s, h);
    a[2] = stage_chunk(ve, (size_t)b*NN + r_, h);
    {
        uint4 w; w.x = (h == 0) ? pk2(gvec[b], 0.f) : 0u;
        w.y = 0u; w.z = 0u; w.w = 0u;
        U4 c; c.u = w; a[3] = c.h;
    }
    f32x16 O = mlp32<4, true>(a, A, WB, lane, h);
    float4 s1, s2;
    s1.x = fmaxf(O[0], 0.f); s1.y = fmaxf(O[1], 0.f);
    s1.z = fmaxf(O[2], 0.f); s1.w = fmaxf(O[3], 0.f);
    s2.x = fmaxf(O[4], 0.f); s2.y = fmaxf(O[5], 0.f);
    s2.z = fmaxf(O[6], 0.f); s2.w = fmaxf(O[7], 0.f);
    *(float4*)(ee + (size_t)e*16 + h*4)     = s1;
    *(float4*)(ee + (size_t)e*16 + h*4 + 8) = s2;
    // Transposed atomic scatter; X time-shared between wave halves (LDS cap).
    float* Xw = X + (wid & 3)*544;
    const int feat = lane & 15;
    if (wid < 4) {
        *(float4*)(Xw + el*17 + h*4)     = s1;
        *(float4*)(Xw + el*17 + h*4 + 8) = s2;
        #pragma unroll
        for (int rr = 0; rr < 8; ++rr) {
            int m = (lane >> 4)*8 + rr;
            float v = Xw[m*17 + feat];
            int rc = __shfl(r_, m);
            int eg = e0 + m;
            atomicAdd(agg + ((size_t)(eg >> 15)*NN + rc)*16 + feat, v);
        }
    }
    __syncthreads();
    if (wid >= 4) {
        *(float4*)(Xw + el*17 + h*4)     = s1;
        *(float4*)(Xw + el*17 + h*4 + 8) = s2;
        #pragma unroll
        for (int rr = 0; rr < 8; ++rr) {
            int m = (lane >> 4)*8 + rr;
            float v = Xw[m*17 + feat];
            int rc = __shfl(r_, m);
            int eg = e0 + m;
            atomicAdd(agg + ((size_t)(eg >> 15)*NN + rc)*16 + feat, v);
        }
    }
}

template<bool DEC>
__device__ __forceinline__ void nu_phase(
    const float* __restrict__ gvec,
    const float* __restrict__ agg, float* __restrict__ ve,
    const u32* __restrict__ B, float* WB,
    const u32* __restrict__ A,               // decode weights (DEC)
    const float* __restrict__ de_bin, const float* __restrict__ de_bh,
    const float* __restrict__ de_bout, float* __restrict__ out,
    int lane, int wid, int el, int h)
{
    const int e = (blockIdx.x*8 + wid)*32 + el;
    const int b = e >> 15;
    bf16x8 a[3];
    a[0] = stage_chunk(agg, (size_t)e, h);
    a[1] = stage_chunk(ve,  (size_t)e, h);
    {
        uint4 w; w.x = (h == 0) ? pk2(gvec[b], 0.f) : 0u;
        w.y = 0u; w.z = 0u; w.w = 0u;
        U4 c; c.u = w; a[2] = c.h;
    }
    f32x16 O = mlp32<3, true>(a, B, WB, lane, h);
    if (!DEC) {
        float4 s1, s2;
        s1.x = fmaxf(O[0], 0.f); s1.y = fmaxf(O[1], 0.f);
        s1.z = fmaxf(O[2], 0.f); s1.w = fmaxf(O[3], 0.f);
        s2.x = fmaxf(O[4], 0.f); s2.y = fmaxf(O[5], 0.f);
        s2.z = fmaxf(O[6], 0.f); s2.w = fmaxf(O[7], 0.f);
        *(float4*)(ve + (size_t)e*16 + h*4)     = s1;
        *(float4*)(ve + (size_t)e*16 + h*4 + 8) = s2;
    } else {
        bf16x8 D0, D1;
        transform32<false>(O, D0, D1);       // relu + pack
        __syncthreads();                     // de DMA drained + pv WB reads done
        stage_bias(WB, de_bin, de_bh, de_bout, 3, (int)threadIdx.x);
        __syncthreads();
        f32x16 O2 = mlp32<1, false>(&D0, A, WB, lane, h);
        if (h == 0) {
            out[(size_t)e*3 + 0] = fmaxf(O2[0], 0.f);
            out[(size_t)e*3 + 1] = fmaxf(O2[1], 0.f);
            out[(size_t)e*3 + 2] = fmaxf(O2[2], 0.f);
        }
    }
}

// ---------------------------------------------------------------------------
// Fused message-passing kernel: eu0 -> nu0 -> eu1 -> nu1+decode.
// 256 blocks x 512 thr, 155KB LDS -> exactly 1 block/CU, all co-resident
// (grid == CU count) -> device-scope spin barrier is safe.
// LDS: A[17920] holds pe (both edge phases), then de (prefetched during nu1);
//      B[17664] holds pv (prefetched at start); WB single bias buffer,
//      restaged per phase; X edge-transpose scratch (4-wave time-share).
// ---------------------------------------------------------------------------
__global__ __launch_bounds__(512, 2) void mp_fused_kernel(
    const float* __restrict__ gvec,
    const int* __restrict__ senders, const int* __restrict__ receivers,
    float* __restrict__ ve, float* __restrict__ ee,
    float* __restrict__ agg0, float* __restrict__ agg1,
    const u32* __restrict__ Wpe, const float* __restrict__ pe_bin,
    const float* __restrict__ Fpe,
    const u32* __restrict__ Wpv, const float* __restrict__ pv_bin,
    const float* __restrict__ Fpv,
    const u32* __restrict__ Wde, const float* __restrict__ de_bin,
    const float* __restrict__ de_bh, const float* __restrict__ de_bout,
    u32* __restrict__ bar, float* __restrict__ out)
{
    __shared__ __align__(16) u32 SL[38848];
    u32* A   = SL;                           // 17920 dw
    u32* B   = SL + 17920;                   // 17664 dw
    float* WB = (float*)(SL + 35584);        // 1088 f
    float* X  = (float*)(SL + 36672);        // 4*544 f
    WAVE_SETUP
    const int tid = threadIdx.x;

    // initial stage: pe -> A, pv -> B, WB <- pe biases
    stage_dma(A, Wpe, 17920, tid);
    stage_dma(B, Wpv, 17664, tid);
    stage_bias(WB, pe_bin, Fpe, Fpe + 1024, 16, tid);
    __syncthreads();                         // drains DMA + LDS writes

    // ---- step 0: edge update (A = pe) ----
    eu_phase(gvec, senders, receivers, ve, ee, agg0, A, WB, X, lane, wid, el, h);
    gridbar(bar + 0);

    // ---- step 0: node update (B = pv) ----
    stage_bias(WB, pv_bin, Fpv, Fpv + 1024, 16, tid);
    __syncthreads();
    nu_phase<false>(gvec, agg0, ve, B, WB, A, de_bin, de_bh, de_bout, out,
                    lane, wid, el, h);
    gridbar(bar + 1);

    // ---- step 1: edge update (A still = pe) ----
    stage_bias(WB, pe_bin, Fpe, Fpe + 1024, 16, tid);
    __syncthreads();
    eu_phase(gvec, senders, receivers, ve, ee, agg1, A, WB, X, lane, wid, el, h);
    gridbar(bar + 2);

    // ---- step 1: node update + fused decode ----
    stage_dma(A, Wde, 17152, tid);           // hidden under pv MLP
    stage_bias(WB, pv_bin, Fpv, Fpv + 1024, 16, tid);
    __syncthreads();
    nu_phase<true>(gvec, agg1, ve, B, WB, A, de_bin, de_bh, de_bout, out,
                   lane, wid, el, h);
}

// ---------------------------------------------------------------------------
// launch
// ---------------------------------------------------------------------------
extern "C" void kernel_launch(void* const* d_in, const int* in_sizes, int n_in,
                              void* d_out, int out_size, void* d_ws, size_t ws_size,
                              hipStream_t stream)
{
    const float* nodes     = (const float*)d_in[0];
    const float* edges     = (const float*)d_in[1];
    const float* gvec      = (const float*)d_in[2];
    const int*   senders   = (const int*)  d_in[3];
    const int*   receivers = (const int*)  d_in[4];

    const float* ne_Win  = (const float*)d_in[5];
    const float* ne_bin  = (const float*)d_in[6];
    const float* ne_Wh   = (const float*)d_in[7];
    const float* ne_bh   = (const float*)d_in[8];
    const float* ne_Wout = (const float*)d_in[9];
    const float* ne_bout = (const float*)d_in[10];

    const float* ed_Win  = (const float*)d_in[11];
    const float* ed_bin  = (const float*)d_in[12];
    const float* ed_Wh   = (const float*)d_in[13];
    const float* ed_bh   = (const float*)d_in[14];
    const float* ed_Wout = (const float*)d_in[15];
    const float* ed_bout = (const float*)d_in[16];

    const float* pe_Win  = (const float*)d_in[17];
    const float* pe_bin  = (const float*)d_in[18];
    const float* pe_Wh   = (const float*)d_in[19];
    const float* pe_bh   = (const float*)d_in[20];
    const float* pe_Wout = (const float*)d_in[21];
    const float* pe_bout = (const float*)d_in[22];
    const float* pe_lng  = (const float*)d_in[23];
    const float* pe_lnb  = (const float*)d_in[24];

    const float* pv_Win  = (const float*)d_in[25];
    const float* pv_bin  = (const float*)d_in[26];
    const float* pv_Wh   = (const float*)d_in[27];
    const float* pv_bh   = (const float*)d_in[28];
    const float* pv_Wout = (const float*)d_in[29];
    const float* pv_bout = (const float*)d_in[30];
    const float* pv_lng  = (const float*)d_in[31];
    const float* pv_lnb  = (const float*)d_in[32];

    const float* de_Win  = (const float*)d_in[33];
    const float* de_bin  = (const float*)d_in[34];
    const float* de_Wh   = (const float*)d_in[35];
    const float* de_bh   = (const float*)d_in[36];
    const float* de_Wout = (const float*)d_in[37];
    const float* de_bout = (const float*)d_in[38];

    // workspace: ve | ee | agg0 | agg1 (4 MB each) | bar(64B) | packed weights
    float* ve   = (float*)d_ws;
    float* ee   = ve   + (size_t)1048576;
    float* agg0 = ee   + (size_t)1048576;
    float* agg1 = agg0 + (size_t)1048576;
    u32* bar = (u32*)(agg1 + (size_t)1048576);
    u32* Wne = bar + 16;
    u32* Wed = Wne + 17152;
    u32* Wpe = Wed + 17152;
    u32* Wpv = Wpe + 17920;
    u32* Wde = Wpv + 17664;
    float* Fpe = (float*)(Wde + 17152);
    float* Fpv = Fpe + 1040;

    prep_kernel<<<350, dim3(256), 0, stream>>>(
        ne_Win, ne_Wh, ne_Wout,
        ed_Win, ed_Wh, ed_Wout,
        pe_Win, pe_Wh, pe_Wout, pe_lng, pe_lnb, pe_bh, pe_bout,
        pv_Win, pv_Wh, pv_Wout, pv_lng, pv_lnb, pv_bh, pv_bout,
        de_Win, de_Wh, de_Wout,
        Wne, Wed, Wpe, Wpv, Wde, Fpe, Fpv);

    // zero agg ping-pong buffers + barrier counters (re-zeroed every launch)
    hipMemsetAsync(agg0, 0, (size_t)2 * 1048576 * sizeof(float) + 64, stream);

    encode_kernel<<<512, dim3(512), 0, stream>>>(nodes, edges, gvec, senders, receivers,
        Wne, ne_bin, ne_bh, ne_bout,
        Wed, ed_bin, ed_bh, ed_bout, ve, ee);

    mp_fused_kernel<<<NBLK, dim3(512), 0, stream>>>(gvec, senders, receivers,
        ve, ee, agg0, agg1,
        Wpe, pe_bin, Fpe,
        Wpv, pv_bin, Fpv,
        Wde, de_bin, de_bh, de_bout,
        bar, (float*)d_out);
}

// Round 4
// 259.595 us; speedup vs baseline: 1.6384x; 1.6384x over previous
//
#include <hip/hip_runtime.h>

#define BB 2
#define NN 32768
#define EN 32768

typedef unsigned int u32;
typedef __attribute__((ext_vector_type(8)))  short bf16x8;
typedef __attribute__((ext_vector_type(2)))  float f32x2;
typedef __attribute__((ext_vector_type(16))) float f32x16;

union U4 { uint4 u; bf16x8 h; };

// Single-instruction bf16 pack (no gfx950 builtin; RNE).
__device__ __forceinline__ u32 pk2(float lo, float hi) {
    u32 r;
    asm("v_cvt_pk_bf16_f32 %0, %1, %2" : "=v"(r) : "v"(lo), "v"(hi));
    return r;
}

// lane<->lane^32 sum via permlane32_swap (VALU, no LDS latency).
__device__ __forceinline__ float xor32_sum(float x) {
    float y = x;
    asm("v_permlane32_swap_b32 %0, %1" : "+v"(x), "+v"(y));
    return x + y;
}

__device__ __forceinline__ f32x16 MF32(bf16x8 a, bf16x8 b, f32x16 c) {
    return __builtin_amdgcn_mfma_f32_32x32x16_bf16(a, b, c, 0, 0, 0);
}

// ---------------------------------------------------------------------------
// 32x32 MFMA engine (round-1 proven layout). Lane (e = lane&31, h = lane>>5).
// C/D: col = e, row(r,h) = (r&3) + 8*(r>>2) + 4h.
// pi: f(t,h,j) = 16t + 4h + (j&3) + 8*(j>>2) -> layer-to-layer pure registers.
// ---------------------------------------------------------------------------
template<bool LN>
__device__ __forceinline__ void transform32(f32x16 D, bf16x8& B0, bf16x8& B1)
{
    f32x2 p0 = {D[0],D[1]},  p1 = {D[2],D[3]},  p2 = {D[4],D[5]},  p3 = {D[6],D[7]};
    f32x2 p4 = {D[8],D[9]},  p5 = {D[10],D[11]},p6 = {D[12],D[13]},p7 = {D[14],D[15]};
    const f32x2 zz = {0.f, 0.f};
    p0 = __builtin_elementwise_max(p0, zz); p1 = __builtin_elementwise_max(p1, zz);
    p2 = __builtin_elementwise_max(p2, zz); p3 = __builtin_elementwise_max(p3, zz);
    p4 = __builtin_elementwise_max(p4, zz); p5 = __builtin_elementwise_max(p5, zz);
    p6 = __builtin_elementwise_max(p6, zz); p7 = __builtin_elementwise_max(p7, zz);
    if (LN) {
        f32x2 sv = ((p0+p1)+(p2+p3)) + ((p4+p5)+(p6+p7));
        f32x2 ta = __builtin_elementwise_fma(p0,p0,
                   __builtin_elementwise_fma(p1,p1,
                   __builtin_elementwise_fma(p2,p2, p3*p3)));
        f32x2 tb = __builtin_elementwise_fma(p4,p4,
                   __builtin_elementwise_fma(p5,p5,
                   __builtin_elementwise_fma(p6,p6, p7*p7)));
        f32x2 tv = ta + tb;
        float s = xor32_sum(sv.x + sv.y);
        float t = xor32_sum(tv.x + tv.y);
        float mu  = s * (1.f/32.f);
        float var = fmaf(-mu, mu, t * (1.f/32.f));
        float rs  = rsqrtf(var + 1e-5f);
        float nt  = -mu * rs;
        f32x2 rs2 = {rs, rs}, nt2 = {nt, nt};
        p0 = __builtin_elementwise_fma(p0, rs2, nt2);
        p1 = __builtin_elementwise_fma(p1, rs2, nt2);
        p2 = __builtin_elementwise_fma(p2, rs2, nt2);
        p3 = __builtin_elementwise_fma(p3, rs2, nt2);
        p4 = __builtin_elementwise_fma(p4, rs2, nt2);
        p5 = __builtin_elementwise_fma(p5, rs2, nt2);
        p6 = __builtin_elementwise_fma(p6, rs2, nt2);
        p7 = __builtin_elementwise_fma(p7, rs2, nt2);
    }
    U4 c;
    c.u.x = pk2(p0.x,p0.y); c.u.y = pk2(p1.x,p1.y);
    c.u.z = pk2(p2.x,p2.y); c.u.w = pk2(p3.x,p3.y);
    B0 = c.h;
    c.u.x = pk2(p4.x,p4.y); c.u.y = pk2(p5.x,p5.y);
    c.u.z = pk2(p6.x,p6.y); c.u.w = pk2(p7.x,p7.y);
    B1 = c.h;
}

// Direct aligned f32x16 LDS load (WB 64B-aligned; h*16 floats = 64B).
__device__ __forceinline__ f32x16 load_biasC(const float* WB, int base, int h) {
    return *(const f32x16*)(WB + base + h*16);
}

// ---------------------------------------------------------------------------
// Dual-chain MLP: two independent 32-element chains per wave share the layer's
// weight fragments and bias C-operand in registers (ds_read once, use twice)
// and interleave for intra-wave MFMA/VALU overlap.
// WL (dwords): [Bin NT*256][Bh 32*512][Bo 512]
// ---------------------------------------------------------------------------
template<int NT, bool LN>
__device__ __forceinline__ void mlp32x2(const bf16x8* aA, const bf16x8* aB,
    f32x16& OA, f32x16& OB, const u32* WL, const float* WB, int lane, int h)
{
    constexpr int HB = NT*256;
    constexpr int BO = HB + 16384;
    U4 c;
    f32x16 DA = load_biasC(WB, 0, h);
    f32x16 DB = DA;
    #pragma unroll
    for (int t = 0; t < NT; ++t) {
        c.u = *(const uint4*)(WL + t*256 + lane*4);
        DA = MF32(c.h, aA[t], DA);
        DB = MF32(c.h, aB[t], DB);
    }
    c.u = *(const uint4*)(WL + HB + lane*4);        bf16x8 w0 = c.h;
    c.u = *(const uint4*)(WL + HB + 256 + lane*4);  bf16x8 w1 = c.h;
    c.u = *(const uint4*)(WL + HB + 512 + lane*4);  bf16x8 x0 = c.h;
    c.u = *(const uint4*)(WL + HB + 768 + lane*4);  bf16x8 x1 = c.h;
    f32x16 pb = load_biasC(WB, 32, h);
    bf16x8 A0, A1, B0, B1;
    transform32<LN>(DA, A0, A1);
    transform32<LN>(DB, B0, B1);
    #pragma unroll 2
    for (int l = 0; l < 32; ++l) {
        const int lp = (l+2 < 32) ? l+2 : 31;
        c.u = *(const uint4*)(WL + HB + lp*512 + lane*4);       bf16x8 nw0 = c.h;
        c.u = *(const uint4*)(WL + HB + lp*512 + 256 + lane*4); bf16x8 nw1 = c.h;
        const int lb_ = (l+1 < 32) ? l+1 : 31;
        f32x16 nb = load_biasC(WB, 32 + lb_*32, h);
        f32x16 EA = MF32(w0, A0, pb);
        EA = MF32(w1, A1, EA);
        f32x16 EB = MF32(w0, B0, pb);
        EB = MF32(w1, B1, EB);
        transform32<LN>(EA, A0, A1);
        transform32<LN>(EB, B0, B1);
        w0 = x0; w1 = x1; x0 = nw0; x1 = nw1; pb = nb;
    }
    c.u = *(const uint4*)(WL + BO + lane*4);        bf16x8 o0 = c.h;
    c.u = *(const uint4*)(WL + BO + 256 + lane*4);  bf16x8 o1 = c.h;
    f32x16 Co = load_biasC(WB, 1056, h);
    OA = MF32(o0, A0, Co);
    OA = MF32(o1, A1, OA);
    OB = MF32(o0, B0, Co);
    OB = MF32(o1, B1, OB);
}

// ---------------------------------------------------------------------------
// Staging (round-1 proven). DMA linear; biases permuted to C-operand layout.
// ---------------------------------------------------------------------------
__device__ __forceinline__ void stage_dma(u32* WL, const u32* __restrict__ Wp,
                                          int wtot, int tid, int nthr)
{
    const int lane = tid & 63;
    const int step = (nthr >> 6) * 256;
    for (int C = (tid >> 6)*256; C < wtot; C += step)
        __builtin_amdgcn_global_load_lds(
            (const __attribute__((address_space(1))) u32*)(Wp + C + lane*4),
            (__attribute__((address_space(3))) u32*)(WL + C), 16, 0, 0);
}

// WB (floats): [0..32) bin | [32..1056) hidden | [1056..1088) out
__device__ __forceinline__ void stage_bias(float* WB,
    const float* __restrict__ bin, const float* __restrict__ bhid,
    const float* __restrict__ bo, int nbo, int tid, int nthr)
{
    for (int i = tid; i < 1088; i += nthr) {
        float v;
        if (i < 32) {
            int w = i, hh = w>>4, r = w&15;
            int f = (r&3) + 8*(r>>2) + 4*hh;
            v = bin[f];
        } else if (i < 1056) {
            int l = (i-32)>>5, w = (i-32)&31, hh = w>>4, r = w&15;
            int f = (r&3) + 8*(r>>2) + 4*hh;
            v = bhid[l*32 + f];
        } else {
            int w = i-1056, hh = w>>4, r = w&15;
            int f = (r&3) + 8*(r>>2) + 4*hh;
            v = (f < nbo) ? bo[f] : 0.f;
        }
        WB[i] = v;
    }
}

__device__ __forceinline__ void stage_weights32(
    u32* WL, float* WB, const u32* __restrict__ Wp,
    const float* __restrict__ bin, const float* __restrict__ bhid,
    const float* __restrict__ bo, int wtot, int nbo, int tid, int nthr)
{
    stage_dma(WL, Wp, wtot, tid, nthr);
    stage_bias(WB, bin, bhid, bo, nbo, tid, nthr);
    __syncthreads();
}

// ---------------------------------------------------------------------------
// prep: weight packing to 32x32 pi layout + LN fold (round-1 verbatim).
// ---------------------------------------------------------------------------
__device__ __forceinline__ void pack_body32(
    const float* __restrict__ Win, const float* __restrict__ Wh,
    const float* __restrict__ Wout, const float* __restrict__ lng,
    u32* __restrict__ dst, int din, int dout, int NT, int lb, int tid)
{
    int t = lb * 256 + tid;
    int binW = NT * 256;
    int tot = binW + 16384 + 512;
    if (t >= tot) return;
    float lo, hi;
    if (t < binW) {
        int tt = t>>8, rem = t&255, ln_ = rem>>2, d = rem&3;
        int hh = ln_>>5, m = ln_&31;
        int f0 = 16*tt + 4*hh + 2*(d&1) + 8*(d>>1);
        lo = (f0   < din) ? Win[f0*32 + m]     : 0.f;
        hi = (f0+1 < din) ? Win[(f0+1)*32 + m] : 0.f;
    } else if (t < binW + 16384) {
        int u = t - binW, l = u>>9, v = u&511;
        int tt = v>>8, rem = v&255, ln_ = rem>>2, d = rem&3;
        int hh = ln_>>5, m = ln_&31;
        int f0 = 16*tt + 4*hh + 2*(d&1) + 8*(d>>1);
        lo = Wh[l*1024 + f0*32 + m];
        hi = Wh[l*1024 + (f0+1)*32 + m];
        if (lng) { lo *= lng[l*32 + f0]; hi *= lng[l*32 + f0 + 1]; }
    } else {
        int u = t - binW - 16384;
        int tt = u>>8, rem = u&255, ln_ = rem>>2, d = rem&3;
        int hh = ln_>>5, m = ln_&31;
        int f0 = 16*tt + 4*hh + 2*(d&1) + 8*(d>>1);
        lo = (m < dout) ? Wout[f0*dout + m]     : 0.f;
        hi = (m < dout) ? Wout[(f0+1)*dout + m] : 0.f;
        if (lng) { lo *= lng[1024 + f0]; hi *= lng[1024 + f0 + 1]; }
    }
    dst[t] = pk2(lo, hi);
}

__device__ __forceinline__ void fold_body(
    const float* __restrict__ Wh,   const float* __restrict__ bh,
    const float* __restrict__ Wout, const float* __restrict__ bout,
    const float* __restrict__ lnb,  float* __restrict__ fb, int lb, int tid)
{
    int j = lb * 256 + tid;
    if (j < 1024) {
        int l = j >> 5, jj = j & 31;
        float acc = bh[j];
        #pragma unroll
        for (int k = 0; k < 32; ++k)
            acc = fmaf(lnb[l*32 + k], Wh[l*1024 + k*32 + jj], acc);
        fb[j] = acc;
    } else if (j < 1024 + 16) {
        int jj = j - 1024;
        float acc = bout[jj];
        #pragma unroll
        for (int k = 0; k < 32; ++k)
            acc = fmaf(lnb[1024 + k], Wout[k*16 + jj], acc);
        fb[j] = acc;
    }
}

__global__ __launch_bounds__(256) void prep_kernel(
    const float* ne_Win, const float* ne_Wh, const float* ne_Wout,
    const float* ed_Win, const float* ed_Wh, const float* ed_Wout,
    const float* pe_Win, const float* pe_Wh, const float* pe_Wout,
    const float* pe_lng, const float* pe_lnb, const float* pe_bh, const float* pe_bout,
    const float* pv_Win, const float* pv_Wh, const float* pv_Wout,
    const float* pv_lng, const float* pv_lnb, const float* pv_bh, const float* pv_bout,
    const float* de_Win, const float* de_Wh, const float* de_Wout,
    u32* Wne, u32* Wed, u32* Wpe, u32* Wpv, u32* Wde,
    float* Fpe, float* Fpv)
{
    int bx = blockIdx.x, tid = threadIdx.x;
    if      (bx < 67)  pack_body32(ne_Win, ne_Wh, ne_Wout, nullptr, Wne,  7, 16, 1, bx,       tid);
    else if (bx < 134) pack_body32(ed_Win, ed_Wh, ed_Wout, nullptr, Wed,  5, 16, 1, bx - 67,  tid);
    else if (bx < 204) pack_body32(pe_Win, pe_Wh, pe_Wout, pe_lng,  Wpe, 49, 16, 4, bx - 134, tid);
    else if (bx < 273) pack_body32(pv_Win, pv_Wh, pv_Wout, pv_lng,  Wpv, 33, 16, 3, bx - 204, tid);
    else if (bx < 340) pack_body32(de_Win, de_Wh, de_Wout, nullptr, Wde, 16,  3, 1, bx - 273, tid);
    else if (bx < 345) fold_body(pe_Wh, pe_bh, pe_Wout, pe_bout, pe_lnb, Fpe, bx - 340, tid);
    else               fold_body(pv_Wh, pv_bh, pv_Wout, pv_bout, pv_lnb, Fpv, bx - 345, tid);
}

__device__ __forceinline__ bf16x8 stage_chunk(const float* __restrict__ arr,
                                              size_t e, int h)
{
    const int off = h*4;
    float4 a = *(const float4*)(arr + e*16 + off);
    float4 b = *(const float4*)(arr + e*16 + off + 8);
    U4 c;
    c.u.x = pk2(a.x, a.y); c.u.y = pk2(a.z, a.w);
    c.u.z = pk2(b.x, b.y); c.u.w = pk2(b.z, b.w);
    return c.h;
}

__device__ __forceinline__ void store_relu(float* __restrict__ dst, size_t e,
                                           int h, f32x16 O)
{
    float4 s1, s2;
    s1.x = fmaxf(O[0], 0.f); s1.y = fmaxf(O[1], 0.f);
    s1.z = fmaxf(O[2], 0.f); s1.w = fmaxf(O[3], 0.f);
    s2.x = fmaxf(O[4], 0.f); s2.y = fmaxf(O[5], 0.f);
    s2.z = fmaxf(O[6], 0.f); s2.w = fmaxf(O[7], 0.f);
    *(float4*)(dst + e*16 + h*4)     = s1;
    *(float4*)(dst + e*16 + h*4 + 8) = s2;
}

#define WAVE_SETUP \
    const int lane = threadIdx.x & 63; \
    const int wid  = threadIdx.x >> 6; \
    const int el = lane & 31, h = lane >> 5;

// ---------------------------------------------------------------------------
// encode: 256-thr blocks (4 waves x 2 chains x 32 el = 256 el), 512 blocks
// -> 2 blocks/CU (73KB LDS), 4 chains/SIMD.
// ---------------------------------------------------------------------------
__device__ __forceinline__ bf16x8 enc_input(bool es, int e, int b,
    const float* __restrict__ nodes, const float* __restrict__ edges,
    const float* __restrict__ gvec,
    const int* __restrict__ senders, const int* __restrict__ receivers, int h)
{
    uint4 w; w.x = 0u; w.y = 0u; w.z = 0u; w.w = 0u;
    if (!es) {
        if (h == 0) {
            float2 v01 = *(const float2*)(nodes + (size_t)e*6);
            float2 v23 = *(const float2*)(nodes + (size_t)e*6 + 2);
            w.x = pk2(v01.x, v01.y); w.y = pk2(v23.x, v23.y);
        } else {
            float2 v45 = *(const float2*)(nodes + (size_t)e*6 + 4);
            w.x = pk2(v45.x, v45.y); w.y = pk2(gvec[b], 0.f);
        }
    } else {
        int s = senders[e], r = receivers[e];
        const float* ps = nodes + ((size_t)b*NN + s)*6;
        const float* pr = nodes + ((size_t)b*NN + r)*6;
        float2 s01 = *(const float2*)ps; float s2v = ps[2];
        float2 r01 = *(const float2*)pr; float r2v = pr[2];
        float r0 = s01.x - r01.x, r1 = s01.y - r01.y, r2 = s2v - r2v;
        if (h == 0) {
            w.x = pk2(edges[e], r0); w.y = pk2(r1, r2);
        } else {
            w.x = pk2(sqrtf(r0*r0 + r1*r1 + r2*r2), 0.f);
        }
    }
    U4 c; c.u = w; return c.h;
}

__global__ __launch_bounds__(256, 2) void encode_kernel(
    const float* __restrict__ nodes, const float* __restrict__ edges,
    const float* __restrict__ gvec,
    const int* __restrict__ senders, const int* __restrict__ receivers,
    const u32* __restrict__ Wne, const float* __restrict__ ne_bin,
    const float* __restrict__ ne_bh, const float* __restrict__ ne_bout,
    const u32* __restrict__ Wed, const float* __restrict__ ed_bin,
    const float* __restrict__ ed_bh, const float* __restrict__ ed_bout,
    float* __restrict__ ve, float* __restrict__ ee)
{
    __shared__ __align__(64) u32 SL[17152 + 1088];
    u32* WL = SL;
    float* WB = (float*)(SL + 17152);
    WAVE_SETUP
    const bool es = blockIdx.x >= 256;
    stage_weights32(WL, WB,
                    es ? Wed : Wne, es ? ed_bin : ne_bin,
                    es ? ed_bh : ne_bh, es ? ed_bout : ne_bout,
                    17152, 16, threadIdx.x, 256);
    const int lb = es ? (blockIdx.x - 256) : blockIdx.x;
    const int eA = (lb*8 + wid*2)*32 + el;
    const int eB = eA + 32;
    const int b = eA >> 15;
    bf16x8 aA = enc_input(es, eA, b, nodes, edges, gvec, senders, receivers, h);
    bf16x8 aB = enc_input(es, eB, b, nodes, edges, gvec, senders, receivers, h);
    float* dst = es ? ee : ve;
    f32x16 OA, OB;
    mlp32x2<1, false>(&aA, &aB, OA, OB, WL, WB, lane, h);
    store_relu(dst, (size_t)eA, h, OA);
    store_relu(dst, (size_t)eB, h, OB);
}

// ---------------------------------------------------------------------------
// edge_update: 256-thr blocks (4 waves x 2 chains), 256 blocks, 1 block/CU.
// ---------------------------------------------------------------------------
__device__ __forceinline__ void scatter_agg(float* Xw, f32x16 O,
    int r_, int e0, float* __restrict__ agg, int lane, int el, int h)
{
    float4 s1, s2;
    s1.x = fmaxf(O[0], 0.f); s1.y = fmaxf(O[1], 0.f);
    s1.z = fmaxf(O[2], 0.f); s1.w = fmaxf(O[3], 0.f);
    s2.x = fmaxf(O[4], 0.f); s2.y = fmaxf(O[5], 0.f);
    s2.z = fmaxf(O[6], 0.f); s2.w = fmaxf(O[7], 0.f);
    *(float4*)(Xw + el*17 + h*4)     = s1;
    *(float4*)(Xw + el*17 + h*4 + 8) = s2;
    const int feat = lane & 15;
    #pragma unroll
    for (int rr = 0; rr < 8; ++rr) {
        int m = (lane >> 4)*8 + rr;
        float v = Xw[m*17 + feat];
        int rc = __shfl(r_, m);                // lane m holds receivers
        int eg = e0 + m;
        atomicAdd(agg + ((size_t)(eg >> 15)*NN + rc)*16 + feat, v);
    }
}

__global__ __launch_bounds__(256, 1) void edge_update_kernel(
    const float* __restrict__ gvec,
    const int* __restrict__ senders, const int* __restrict__ receivers,
    const float* __restrict__ ve, float* __restrict__ ee, float* __restrict__ agg,
    const u32* __restrict__ Wp, const float* __restrict__ bin,
    const float* __restrict__ fb)
{
    __shared__ __align__(64) u32 SL[17920 + 1088 + 4*544];
    u32* WL = SL;
    float* WB = (float*)(SL + 17920);
    WAVE_SETUP
    float* Xw = (float*)(SL + 19008) + wid*544;
    stage_weights32(WL, WB, Wp, bin, fb, fb + 1024, 17920, 16, threadIdx.x, 256);
    const int e0A = (blockIdx.x*8 + wid*2)*32;
    const int e0B = e0A + 32;
    const int eA = e0A + el, eB = e0B + el;
    const int b  = eA >> 15;
    const int sA = senders[eA], rA = receivers[eA];
    const int sB = senders[eB], rB = receivers[eB];
    bf16x8 aA[4], aB[4];
    aA[0] = stage_chunk(ee, (size_t)eA, h);
    aB[0] = stage_chunk(ee, (size_t)eB, h);
    aA[1] = stage_chunk(ve, (size_t)b*NN + sA, h);
    aB[1] = stage_chunk(ve, (size_t)b*NN + sB, h);
    aA[2] = stage_chunk(ve, (size_t)b*NN + rA, h);
    aB[2] = stage_chunk(ve, (size_t)b*NN + rB, h);
    {
        uint4 w; w.x = (h == 0) ? pk2(gvec[b], 0.f) : 0u;
        w.y = 0u; w.z = 0u; w.w = 0u;
        U4 c; c.u = w; aA[3] = c.h; aB[3] = c.h;
    }
    f32x16 OA, OB;
    mlp32x2<4, true>(aA, aB, OA, OB, WL, WB, lane, h);
    store_relu(ee, (size_t)eA, h, OA);
    store_relu(ee, (size_t)eB, h, OB);
    // Transposed atomic scatter, one group at a time through wave-private LDS
    // (same-wave LDS ordering; no barriers).
    scatter_agg(Xw, OA, rA, e0A, agg, lane, el, h);
    scatter_agg(Xw, OB, rB, e0B, agg, lane, el, h);
}

// ---------------------------------------------------------------------------
// node_update: 256-thr blocks (4 waves x 2 chains), 256 blocks, 1 block/CU.
// DEC=true: restage decode weights over the same WL after a barrier; node
// output regs ARE decode's input B-frag under pi (identity).
// ---------------------------------------------------------------------------
template<bool DEC>
__global__ __launch_bounds__(256, 1) void node_update_kernel(
    const float* __restrict__ gvec,
    const float* __restrict__ agg, float* __restrict__ ve,
    const u32* __restrict__ Wp, const float* __restrict__ bin,
    const float* __restrict__ fb,
    const u32* __restrict__ Wde, const float* __restrict__ de_bin,
    const float* __restrict__ de_bh, const float* __restrict__ de_bout,
    float* __restrict__ out)
{
    __shared__ __align__(64) u32 SL[17664 + 1088];
    u32* WL = SL;
    float* WB = (float*)(SL + 17664);
    WAVE_SETUP
    stage_weights32(WL, WB, Wp, bin, fb, fb + 1024, 17664, 16, threadIdx.x, 256);
    const int eA = (blockIdx.x*8 + wid*2)*32 + el;
    const int eB = eA + 32;
    const int b = eA >> 15;
    bf16x8 aA[3], aB[3];
    aA[0] = stage_chunk(agg, (size_t)eA, h);
    aB[0] = stage_chunk(agg, (size_t)eB, h);
    aA[1] = stage_chunk(ve,  (size_t)eA, h);
    aB[1] = stage_chunk(ve,  (size_t)eB, h);
    {
        uint4 w; w.x = (h == 0) ? pk2(gvec[b], 0.f) : 0u;
        w.y = 0u; w.z = 0u; w.w = 0u;
        U4 c; c.u = w; aA[2] = c.h; aB[2] = c.h;
    }
    f32x16 OA, OB;
    mlp32x2<3, true>(aA, aB, OA, OB, WL, WB, lane, h);
    if (!DEC) {
        store_relu(ve, (size_t)eA, h, OA);
        store_relu(ve, (size_t)eB, h, OB);
    } else {
        bf16x8 dA0, dA1, dB0, dB1;
        transform32<false>(OA, dA0, dA1);    // relu + pack
        transform32<false>(OB, dB0, dB1);
        __syncthreads();                     // all waves done with pv weights
        stage_weights32(WL, WB, Wde, de_bin, de_bh, de_bout, 17152, 3,
                        threadIdx.x, 256);   // ends in barrier
        f32x16 QA, QB;
        mlp32x2<1, false>(&dA0, &dB0, QA, QB, WL, WB, lane, h);
        if (h == 0) {
            out[(size_t)eA*3 + 0] = fmaxf(QA[0], 0.f);
            out[(size_t)eA*3 + 1] = fmaxf(QA[1], 0.f);
            out[(size_t)eA*3 + 2] = fmaxf(QA[2], 0.f);
            out[(size_t)eB*3 + 0] = fmaxf(QB[0], 0.f);
            out[(size_t)eB*3 + 1] = fmaxf(QB[1], 0.f);
            out[(size_t)eB*3 + 2] = fmaxf(QB[2], 0.f);
        }
    }
}

// ---------------------------------------------------------------------------
// launch
// ---------------------------------------------------------------------------
extern "C" void kernel_launch(void* const* d_in, const int* in_sizes, int n_in,
                              void* d_out, int out_size, void* d_ws, size_t ws_size,
                              hipStream_t stream)
{
    const float* nodes     = (const float*)d_in[0];
    const float* edges     = (const float*)d_in[1];
    const float* gvec      = (const float*)d_in[2];
    const int*   senders   = (const int*)  d_in[3];
    const int*   receivers = (const int*)  d_in[4];

    const float* ne_Win  = (const float*)d_in[5];
    const float* ne_bin  = (const float*)d_in[6];
    const float* ne_Wh   = (const float*)d_in[7];
    const float* ne_bh   = (const float*)d_in[8];
    const float* ne_Wout = (const float*)d_in[9];
    const float* ne_bout = (const float*)d_in[10];

    const float* ed_Win  = (const float*)d_in[11];
    const float* ed_bin  = (const float*)d_in[12];
    const float* ed_Wh   = (const float*)d_in[13];
    const float* ed_bh   = (const float*)d_in[14];
    const float* ed_Wout = (const float*)d_in[15];
    const float* ed_bout = (const float*)d_in[16];

    const float* pe_Win  = (const float*)d_in[17];
    const float* pe_bin  = (const float*)d_in[18];
    const float* pe_Wh   = (const float*)d_in[19];
    const float* pe_bh   = (const float*)d_in[20];
    const float* pe_Wout = (const float*)d_in[21];
    const float* pe_bout = (const float*)d_in[22];
    const float* pe_lng  = (const float*)d_in[23];
    const float* pe_lnb  = (const float*)d_in[24];

    const float* pv_Win  = (const float*)d_in[25];
    const float* pv_bin  = (const float*)d_in[26];
    const float* pv_Wh   = (const float*)d_in[27];
    const float* pv_bh   = (const float*)d_in[28];
    const float* pv_Wout = (const float*)d_in[29];
    const float* pv_bout = (const float*)d_in[30];
    const float* pv_lng  = (const float*)d_in[31];
    const float* pv_lnb  = (const float*)d_in[32];

    const float* de_Win  = (const float*)d_in[33];
    const float* de_bin  = (const float*)d_in[34];
    const float* de_Wh   = (const float*)d_in[35];
    const float* de_bh   = (const float*)d_in[36];
    const float* de_Wout = (const float*)d_in[37];
    const float* de_bout = (const float*)d_in[38];

    // workspace: ve | ee | agg0 | agg1 (4 MB each) | packed weights | biases
    float* ve   = (float*)d_ws;
    float* ee   = ve   + (size_t)1048576;
    float* agg0 = ee   + (size_t)1048576;
    float* agg1 = agg0 + (size_t)1048576;
    u32* Wne = (u32*)(agg1 + (size_t)1048576);
    u32* Wed = Wne + 17152;
    u32* Wpe = Wed + 17152;
    u32* Wpv = Wpe + 17920;
    u32* Wde = Wpv + 17664;
    float* Fpe = (float*)(Wde + 17152);
    float* Fpv = Fpe + 1040;

    prep_kernel<<<350, dim3(256), 0, stream>>>(
        ne_Win, ne_Wh, ne_Wout,
        ed_Win, ed_Wh, ed_Wout,
        pe_Win, pe_Wh, pe_Wout, pe_lng, pe_lnb, pe_bh, pe_bout,
        pv_Win, pv_Wh, pv_Wout, pv_lng, pv_lnb, pv_bh, pv_bout,
        de_Win, de_Wh, de_Wout,
        Wne, Wed, Wpe, Wpv, Wde, Fpe, Fpv);

    // zero both agg ping-pong buffers in one shot
    hipMemsetAsync(agg0, 0, (size_t)2 * 1048576 * sizeof(float), stream);

    encode_kernel<<<512, dim3(256), 0, stream>>>(nodes, edges, gvec, senders, receivers,
        Wne, ne_bin, ne_bh, ne_bout,
        Wed, ed_bin, ed_bh, ed_bout, ve, ee);

    // step 0
    edge_update_kernel<<<256, dim3(256), 0, stream>>>(gvec, senders, receivers,
        ve, ee, agg0, Wpe, pe_bin, Fpe);
    node_update_kernel<false><<<256, dim3(256), 0, stream>>>(gvec, agg0, ve,
        Wpv, pv_bin, Fpv, Wde, de_bin, de_bh, de_bout, (float*)d_out);
    // step 1 (+ fused decode)
    edge_update_kernel<<<256, dim3(256), 0, stream>>>(gvec, senders, receivers,
        ve, ee, agg1, Wpe, pe_bin, Fpe);
    node_update_kernel<true><<<256, dim3(256), 0, stream>>>(gvec, agg1, ve,
        Wpv, pv_bin, Fpv, Wde, de_bin, de_bh, de_bout, (float*)d_out);
}

// Round 5
// 244.139 us; speedup vs baseline: 1.7422x; 1.0633x over previous
//
#include <hip/hip_runtime.h>

#define BB 2
#define NN 32768
#define EN 32768

typedef unsigned int u32;
typedef __attribute__((ext_vector_type(8)))  short bf16x8;
typedef __attribute__((ext_vector_type(2)))  float f32x2;
typedef __attribute__((ext_vector_type(16))) float f32x16;

union U4 { uint4 u; bf16x8 h; };

// Single-instruction bf16 pack (no gfx950 builtin; RNE).
__device__ __forceinline__ u32 pk2(float lo, float hi) {
    u32 r;
    asm("v_cvt_pk_bf16_f32 %0, %1, %2" : "=v"(r) : "v"(lo), "v"(hi));
    return r;
}

// lane<->lane^32 sum via permlane32_swap (VALU, no LDS latency).
__device__ __forceinline__ float xor32_sum(float x) {
    float y = x;
    asm("v_permlane32_swap_b32 %0, %1" : "+v"(x), "+v"(y));
    return x + y;
}

__device__ __forceinline__ f32x16 MF32(bf16x8 a, bf16x8 b, f32x16 c) {
    return __builtin_amdgcn_mfma_f32_32x32x16_bf16(a, b, c, 0, 0, 0);
}

// ---------------------------------------------------------------------------
// 32x32 MFMA engine. Lane (e = lane&31, h = lane>>5).
// C/D: col = e (ELEMENT), row(r,h) = (r&3) + 8*(r>>2) + 4h (FEATURE).
// pi: f(t,h,j) = 16t + 4h + (j&3) + 8*(j>>2) -> layer-to-layer pure registers.
// Key property for the LN-commute: all 16 C-values of a lane belong to one
// element, so LN stats (mu, rs) are lane-scalars.
// ---------------------------------------------------------------------------
template<bool LN>
__device__ __forceinline__ void transform32(f32x16 D, bf16x8& B0, bf16x8& B1)
{
    f32x2 p0 = {D[0],D[1]},  p1 = {D[2],D[3]},  p2 = {D[4],D[5]},  p3 = {D[6],D[7]};
    f32x2 p4 = {D[8],D[9]},  p5 = {D[10],D[11]},p6 = {D[12],D[13]},p7 = {D[14],D[15]};
    const f32x2 zz = {0.f, 0.f};
    p0 = __builtin_elementwise_max(p0, zz); p1 = __builtin_elementwise_max(p1, zz);
    p2 = __builtin_elementwise_max(p2, zz); p3 = __builtin_elementwise_max(p3, zz);
    p4 = __builtin_elementwise_max(p4, zz); p5 = __builtin_elementwise_max(p5, zz);
    p6 = __builtin_elementwise_max(p6, zz); p7 = __builtin_elementwise_max(p7, zz);
    if (LN) {
        f32x2 sv = ((p0+p1)+(p2+p3)) + ((p4+p5)+(p6+p7));
        f32x2 ta = __builtin_elementwise_fma(p0,p0,
                   __builtin_elementwise_fma(p1,p1,
                   __builtin_elementwise_fma(p2,p2, p3*p3)));
        f32x2 tb = __builtin_elementwise_fma(p4,p4,
                   __builtin_elementwise_fma(p5,p5,
                   __builtin_elementwise_fma(p6,p6, p7*p7)));
        f32x2 tv = ta + tb;
        float s = xor32_sum(sv.x + sv.y);
        float t = xor32_sum(tv.x + tv.y);
        float mu  = s * (1.f/32.f);
        float var = fmaf(-mu, mu, t * (1.f/32.f));
        float rs  = rsqrtf(var + 1e-5f);
        float nt  = -mu * rs;
        f32x2 rs2 = {rs, rs}, nt2 = {nt, nt};
        p0 = __builtin_elementwise_fma(p0, rs2, nt2);
        p1 = __builtin_elementwise_fma(p1, rs2, nt2);
        p2 = __builtin_elementwise_fma(p2, rs2, nt2);
        p3 = __builtin_elementwise_fma(p3, rs2, nt2);
        p4 = __builtin_elementwise_fma(p4, rs2, nt2);
        p5 = __builtin_elementwise_fma(p5, rs2, nt2);
        p6 = __builtin_elementwise_fma(p6, rs2, nt2);
        p7 = __builtin_elementwise_fma(p7, rs2, nt2);
    }
    U4 c;
    c.u.x = pk2(p0.x,p0.y); c.u.y = pk2(p1.x,p1.y);
    c.u.z = pk2(p2.x,p2.y); c.u.w = pk2(p3.x,p3.y);
    B0 = c.h;
    c.u.x = pk2(p4.x,p4.y); c.u.y = pk2(p5.x,p5.y);
    c.u.z = pk2(p6.x,p6.y); c.u.w = pk2(p7.x,p7.y);
    B1 = c.h;
}

// LN stats of relu'd activations held as 8 f32x2 pairs (16 features/lane;
// partner lane^32 holds the other 16). rs = rsqrt(var+eps), q = -mu*rs.
__device__ __forceinline__ void stats8(
    f32x2 p0, f32x2 p1, f32x2 p2, f32x2 p3,
    f32x2 p4, f32x2 p5, f32x2 p6, f32x2 p7, float& rs, float& q)
{
    f32x2 sv = ((p0+p1)+(p2+p3)) + ((p4+p5)+(p6+p7));
    f32x2 ta = __builtin_elementwise_fma(p0,p0,
               __builtin_elementwise_fma(p1,p1,
               __builtin_elementwise_fma(p2,p2, p3*p3)));
    f32x2 tb = __builtin_elementwise_fma(p4,p4,
               __builtin_elementwise_fma(p5,p5,
               __builtin_elementwise_fma(p6,p6, p7*p7)));
    f32x2 tv = ta + tb;
    float s = xor32_sum(sv.x + sv.y);
    float t = xor32_sum(tv.x + tv.y);
    float mu  = s * (1.f/32.f);
    float var = fmaf(-mu, mu, t * (1.f/32.f));
    rs = rsqrtf(var + 1e-5f);
    q  = -mu * rs;
}

// Direct aligned f32x16 LDS load (WB 64B-aligned; h*16 floats = 64B).
__device__ __forceinline__ f32x16 load_biasC(const float* WB, int base, int h) {
    return *(const f32x16*)(WB + base + h*16);
}

// ---------------------------------------------------------------------------
// OLD path (non-LN MLPs: encode, decode). Round-1 proven.
// WL (dwords): [Bin NT*256][Bh 32*512][Bo 512]
// ---------------------------------------------------------------------------
template<int NT, bool LN>
__device__ __forceinline__ f32x16 mlp32(const bf16x8* bIn,
    const u32* WL, const float* WB, int lane, int h)
{
    constexpr int HB = NT*256;
    constexpr int BO = HB + 16384;
    U4 c;
    f32x16 D = load_biasC(WB, 0, h);
    #pragma unroll
    for (int t = 0; t < NT; ++t) {
        c.u = *(const uint4*)(WL + t*256 + lane*4);
        D = MF32(c.h, bIn[t], D);
    }
    c.u = *(const uint4*)(WL + HB + lane*4);        bf16x8 w0 = c.h;
    c.u = *(const uint4*)(WL + HB + 256 + lane*4);  bf16x8 w1 = c.h;
    c.u = *(const uint4*)(WL + HB + 512 + lane*4);  bf16x8 x0 = c.h;
    c.u = *(const uint4*)(WL + HB + 768 + lane*4);  bf16x8 x1 = c.h;
    f32x16 pb = load_biasC(WB, 32, h);
    bf16x8 B0, B1;
    transform32<LN>(D, B0, B1);
    #pragma unroll 4
    for (int l = 0; l < 32; ++l) {
        const int lp = (l+2 < 32) ? l+2 : 31;
        c.u = *(const uint4*)(WL + HB + lp*512 + lane*4);       bf16x8 nw0 = c.h;
        c.u = *(const uint4*)(WL + HB + lp*512 + 256 + lane*4); bf16x8 nw1 = c.h;
        const int lb_ = (l+1 < 32) ? l+1 : 31;
        f32x16 nb = load_biasC(WB, 32 + lb_*32, h);
        f32x16 E = MF32(w0, B0, pb);
        E = MF32(w1, B1, E);
        transform32<LN>(E, B0, B1);
        w0 = x0; w1 = x1; x0 = nw0; x1 = nw1; pb = nb;
    }
    c.u = *(const uint4*)(WL + BO + lane*4);        bf16x8 o0 = c.h;
    c.u = *(const uint4*)(WL + BO + 256 + lane*4);  bf16x8 o1 = c.h;
    f32x16 Co = load_biasC(WB, 1056, h);
    f32x16 O = MF32(o0, B0, Co);
    O = MF32(o1, B1, O);
    return O;
}

// ---------------------------------------------------------------------------
// NEW path (LN MLPs: pe, pv). LN commuted through the next linear layer:
//   W.((h-mu)*rs) = rs*(W.h) - mu*rs*rowsum(W)
// so the MFMA consumes RAW relu output (pack immediately) and normalization
// becomes a post-MFMA lane-scalar fma: P = rs*E' + (beta + q*rho), q=-mu*rs.
// The LN-stats chain (sum/permlane/rsqrt) runs in PARALLEL with the MFMAs.
// The two K=16 MFMAs are independent (C=0), combined by the scale fmas.
// WBln (floats): [0..32) binC | per layer l: beta at 32+l*64, rho at 64+l*64
//               | out: beta at 2080, rho at 2112. Total 2144.
// ---------------------------------------------------------------------------
#define LN_POST(E1, E2) \
    { \
        f32x2 q2 = {q, q}, rs2 = {rs, rs}; \
        f32x2 b0 = {bet[0],bet[1]}, b1 = {bet[2],bet[3]}, b2 = {bet[4],bet[5]}, b3 = {bet[6],bet[7]}; \
        f32x2 b4 = {bet[8],bet[9]}, b5 = {bet[10],bet[11]}, b6 = {bet[12],bet[13]}, b7 = {bet[14],bet[15]}; \
        f32x2 r0 = {rho[0],rho[1]}, r1 = {rho[2],rho[3]}, r2 = {rho[4],rho[5]}, r3 = {rho[6],rho[7]}; \
        f32x2 r4 = {rho[8],rho[9]}, r5 = {rho[10],rho[11]}, r6 = {rho[12],rho[13]}, r7 = {rho[14],rho[15]}; \
        f32x2 c0 = __builtin_elementwise_fma(q2, r0, b0); \
        f32x2 c1 = __builtin_elementwise_fma(q2, r1, b1); \
        f32x2 c2 = __builtin_elementwise_fma(q2, r2, b2); \
        f32x2 c3 = __builtin_elementwise_fma(q2, r3, b3); \
        f32x2 c4 = __builtin_elementwise_fma(q2, r4, b4); \
        f32x2 c5 = __builtin_elementwise_fma(q2, r5, b5); \
        f32x2 c6 = __builtin_elementwise_fma(q2, r6, b6); \
        f32x2 c7 = __builtin_elementwise_fma(q2, r7, b7); \
        f32x2 e; \
        e = (f32x2){E1[0],E1[1]};   c0 = __builtin_elementwise_fma(rs2, e, c0); \
        e = (f32x2){E1[2],E1[3]};   c1 = __builtin_elementwise_fma(rs2, e, c1); \
        e = (f32x2){E1[4],E1[5]};   c2 = __builtin_elementwise_fma(rs2, e, c2); \
        e = (f32x2){E1[6],E1[7]};   c3 = __builtin_elementwise_fma(rs2, e, c3); \
        e = (f32x2){E1[8],E1[9]};   c4 = __builtin_elementwise_fma(rs2, e, c4); \
        e = (f32x2){E1[10],E1[11]}; c5 = __builtin_elementwise_fma(rs2, e, c5); \
        e = (f32x2){E1[12],E1[13]}; c6 = __builtin_elementwise_fma(rs2, e, c6); \
        e = (f32x2){E1[14],E1[15]}; c7 = __builtin_elementwise_fma(rs2, e, c7); \
        e = (f32x2){E2[0],E2[1]};   p0 = __builtin_elementwise_fma(rs2, e, c0); \
        e = (f32x2){E2[2],E2[3]};   p1 = __builtin_elementwise_fma(rs2, e, c1); \
        e = (f32x2){E2[4],E2[5]};   p2 = __builtin_elementwise_fma(rs2, e, c2); \
        e = (f32x2){E2[6],E2[7]};   p3 = __builtin_elementwise_fma(rs2, e, c3); \
        e = (f32x2){E2[8],E2[9]};   p4 = __builtin_elementwise_fma(rs2, e, c4); \
        e = (f32x2){E2[10],E2[11]}; p5 = __builtin_elementwise_fma(rs2, e, c5); \
        e = (f32x2){E2[12],E2[13]}; p6 = __builtin_elementwise_fma(rs2, e, c6); \
        e = (f32x2){E2[14],E2[15]}; p7 = __builtin_elementwise_fma(rs2, e, c7); \
    }

template<int NT>
__device__ __forceinline__ f32x16 mlp32_ln(const bf16x8* bIn,
    const u32* WL, const float* WB, int lane, int h)
{
    constexpr int HB = NT*256;
    constexpr int BO = HB + 16384;
    U4 c;
    f32x16 Z;
    #pragma unroll
    for (int i = 0; i < 16; ++i) Z[i] = 0.f;
    // layer 0: bias-as-C (input not normalized)
    f32x16 D = load_biasC(WB, 0, h);
    #pragma unroll
    for (int t = 0; t < NT; ++t) {
        c.u = *(const uint4*)(WL + t*256 + lane*4);
        D = MF32(c.h, bIn[t], D);
    }
    const f32x2 zz = {0.f, 0.f};
    f32x2 p0 = {D[0],D[1]},  p1 = {D[2],D[3]},  p2 = {D[4],D[5]},  p3 = {D[6],D[7]};
    f32x2 p4 = {D[8],D[9]},  p5 = {D[10],D[11]},p6 = {D[12],D[13]},p7 = {D[14],D[15]};
    p0 = __builtin_elementwise_max(p0, zz); p1 = __builtin_elementwise_max(p1, zz);
    p2 = __builtin_elementwise_max(p2, zz); p3 = __builtin_elementwise_max(p3, zz);
    p4 = __builtin_elementwise_max(p4, zz); p5 = __builtin_elementwise_max(p5, zz);
    p6 = __builtin_elementwise_max(p6, zz); p7 = __builtin_elementwise_max(p7, zz);
    float rs, q;
    stats8(p0,p1,p2,p3,p4,p5,p6,p7, rs, q);
    bf16x8 H0, H1;
    {
        U4 cc;
        cc.u.x = pk2(p0.x,p0.y); cc.u.y = pk2(p1.x,p1.y);
        cc.u.z = pk2(p2.x,p2.y); cc.u.w = pk2(p3.x,p3.y); H0 = cc.h;
        cc.u.x = pk2(p4.x,p4.y); cc.u.y = pk2(p5.x,p5.y);
        cc.u.z = pk2(p6.x,p6.y); cc.u.w = pk2(p7.x,p7.y); H1 = cc.h;
    }
    c.u = *(const uint4*)(WL + HB + lane*4);        bf16x8 w0 = c.h;
    c.u = *(const uint4*)(WL + HB + 256 + lane*4);  bf16x8 w1 = c.h;
    c.u = *(const uint4*)(WL + HB + 512 + lane*4);  bf16x8 x0 = c.h;
    c.u = *(const uint4*)(WL + HB + 768 + lane*4);  bf16x8 x1 = c.h;
    f32x16 bet = load_biasC(WB, 32, h);
    f32x16 rho = load_biasC(WB, 64, h);
    #pragma unroll 2
    for (int l = 0; l < 32; ++l) {
        f32x16 E1 = MF32(w0, H0, Z);
        f32x16 E2 = MF32(w1, H1, Z);
        const int lp = (l+2 < 32) ? l+2 : 31;
        c.u = *(const uint4*)(WL + HB + lp*512 + lane*4);       bf16x8 nw0 = c.h;
        c.u = *(const uint4*)(WL + HB + lp*512 + 256 + lane*4); bf16x8 nw1 = c.h;
        const int lb_ = (l+1 < 32) ? l+1 : 31;
        f32x16 betN = load_biasC(WB, 32 + lb_*64, h);
        f32x16 rhoN = load_biasC(WB, 64 + lb_*64, h);
        LN_POST(E1, E2)
        p0 = __builtin_elementwise_max(p0, zz); p1 = __builtin_elementwise_max(p1, zz);
        p2 = __builtin_elementwise_max(p2, zz); p3 = __builtin_elementwise_max(p3, zz);
        p4 = __builtin_elementwise_max(p4, zz); p5 = __builtin_elementwise_max(p5, zz);
        p6 = __builtin_elementwise_max(p6, zz); p7 = __builtin_elementwise_max(p7, zz);
        stats8(p0,p1,p2,p3,p4,p5,p6,p7, rs, q);
        {
            U4 cc;
            cc.u.x = pk2(p0.x,p0.y); cc.u.y = pk2(p1.x,p1.y);
            cc.u.z = pk2(p2.x,p2.y); cc.u.w = pk2(p3.x,p3.y); H0 = cc.h;
            cc.u.x = pk2(p4.x,p4.y); cc.u.y = pk2(p5.x,p5.y);
            cc.u.z = pk2(p6.x,p6.y); cc.u.w = pk2(p7.x,p7.y); H1 = cc.h;
        }
        w0 = x0; w1 = x1; x0 = nw0; x1 = nw1; bet = betN; rho = rhoN;
    }
    // out layer (same commute; beta/rho at 2080/2112)
    c.u = *(const uint4*)(WL + BO + lane*4);        bf16x8 o0 = c.h;
    c.u = *(const uint4*)(WL + BO + 256 + lane*4);  bf16x8 o1 = c.h;
    bet = load_biasC(WB, 2080, h);
    rho = load_biasC(WB, 2112, h);
    f32x16 E1 = MF32(o0, H0, Z);
    f32x16 E2 = MF32(o1, H1, Z);
    LN_POST(E1, E2)
    f32x16 O = {p0.x,p0.y, p1.x,p1.y, p2.x,p2.y, p3.x,p3.y,
                p4.x,p4.y, p5.x,p5.y, p6.x,p6.y, p7.x,p7.y};
    return O;
}

// ---------------------------------------------------------------------------
// Staging. DMA linear; biases permuted to the C-operand layout.
// ---------------------------------------------------------------------------
__device__ __forceinline__ void stage_dma(u32* WL, const u32* __restrict__ Wp,
                                          int wtot, int tid, int nthr)
{
    const int lane = tid & 63;
    const int step = (nthr >> 6) * 256;
    for (int C = (tid >> 6)*256; C < wtot; C += step)
        __builtin_amdgcn_global_load_lds(
            (const __attribute__((address_space(1))) u32*)(Wp + C + lane*4),
            (__attribute__((address_space(3))) u32*)(WL + C), 16, 0, 0);
}

// OLD bias staging (non-LN): WB [0..32) bin | [32..1056) hidden | [1056..1088) out
__device__ __forceinline__ void stage_bias(float* WB,
    const float* __restrict__ bin, const float* __restrict__ bhid,
    const float* __restrict__ bo, int nbo, int tid, int nthr)
{
    for (int i = tid; i < 1088; i += nthr) {
        float v;
        if (i < 32) {
            int w = i, hh = w>>4, r = w&15;
            int f = (r&3) + 8*(r>>2) + 4*hh;
            v = bin[f];
        } else if (i < 1056) {
            int l = (i-32)>>5, w = (i-32)&31, hh = w>>4, r = w&15;
            int f = (r&3) + 8*(r>>2) + 4*hh;
            v = bhid[l*32 + f];
        } else {
            int w = i-1056, hh = w>>4, r = w&15;
            int f = (r&3) + 8*(r>>2) + 4*hh;
            v = (f < nbo) ? bo[f] : 0.f;
        }
        WB[i] = v;
    }
}

// NEW bias staging (LN): F layout [0..1024) fb_h | [1024..1040) fb_out |
// [1040..2064) rho_h | [2064..2080) rho_out.
__device__ __forceinline__ void stage_bias_ln(float* WB,
    const float* __restrict__ bin, const float* __restrict__ F,
    int tid, int nthr)
{
    for (int i = tid; i < 2144; i += nthr) {
        float v;
        if (i < 32) {
            int hh = i>>4, r = i&15;
            int f = (r&3) + 8*(r>>2) + 4*hh;
            v = bin[f];
        } else {
            int u = i - 32, l = u>>6, w = u&63, sel = w>>5, ww = w&31;
            int hh = ww>>4, r = ww&15;
            int f = (r&3) + 8*(r>>2) + 4*hh;
            if (l < 32) v = sel ? F[1040 + l*32 + f] : F[l*32 + f];
            else        v = (f < 16) ? (sel ? F[2064 + f] : F[1024 + f]) : 0.f;
        }
        WB[i] = v;
    }
}

__device__ __forceinline__ void stage_weights32(
    u32* WL, float* WB, const u32* __restrict__ Wp,
    const float* __restrict__ bin, const float* __restrict__ bhid,
    const float* __restrict__ bo, int wtot, int nbo, int tid, int nthr)
{
    stage_dma(WL, Wp, wtot, tid, nthr);
    stage_bias(WB, bin, bhid, bo, nbo, tid, nthr);
    __syncthreads();
}

__device__ __forceinline__ void stage_weights32_ln(
    u32* WL, float* WB, const u32* __restrict__ Wp,
    const float* __restrict__ bin, const float* __restrict__ F,
    int wtot, int tid, int nthr)
{
    stage_dma(WL, Wp, wtot, tid, nthr);
    stage_bias_ln(WB, bin, F, tid, nthr);
    __syncthreads();
}

// ---------------------------------------------------------------------------
// prep: weight packing to 32x32 pi layout + folds.
// ---------------------------------------------------------------------------
__device__ __forceinline__ void pack_body32(
    const float* __restrict__ Win, const float* __restrict__ Wh,
    const float* __restrict__ Wout, const float* __restrict__ lng,
    u32* __restrict__ dst, int din, int dout, int NT, int lb, int tid)
{
    int t = lb * 256 + tid;
    int binW = NT * 256;
    int tot = binW + 16384 + 512;
    if (t >= tot) return;
    float lo, hi;
    if (t < binW) {
        int tt = t>>8, rem = t&255, ln_ = rem>>2, d = rem&3;
        int hh = ln_>>5, m = ln_&31;
        int f0 = 16*tt + 4*hh + 2*(d&1) + 8*(d>>1);
        lo = (f0   < din) ? Win[f0*32 + m]     : 0.f;
        hi = (f0+1 < din) ? Win[(f0+1)*32 + m] : 0.f;
    } else if (t < binW + 16384) {
        int u = t - binW, l = u>>9, v = u&511;
        int tt = v>>8, rem = v&255, ln_ = rem>>2, d = rem&3;
        int hh = ln_>>5, m = ln_&31;
        int f0 = 16*tt + 4*hh + 2*(d&1) + 8*(d>>1);
        lo = Wh[l*1024 + f0*32 + m];
        hi = Wh[l*1024 + (f0+1)*32 + m];
        if (lng) { lo *= lng[l*32 + f0]; hi *= lng[l*32 + f0 + 1]; }
    } else {
        int u = t - binW - 16384;
        int tt = u>>8, rem = u&255, ln_ = rem>>2, d = rem&3;
        int hh = ln_>>5, m = ln_&31;
        int f0 = 16*tt + 4*hh + 2*(d&1) + 8*(d>>1);
        lo = (m < dout) ? Wout[f0*dout + m]     : 0.f;
        hi = (m < dout) ? Wout[(f0+1)*dout + m] : 0.f;
        if (lng) { lo *= lng[1024 + f0]; hi *= lng[1024 + f0 + 1]; }
    }
    dst[t] = pk2(lo, hi);
}

// dst[j<1024] = (bh?bh[j]:0) + sum_k vec[l*32+k]*Wh[l][k][jj]
// dst[1024+jj] = (bout?bout[jj]:0) + sum_k vec[1024+k]*Wout[k][jj]
__device__ __forceinline__ void fold_body(
    const float* __restrict__ Wh,   const float* __restrict__ bh,
    const float* __restrict__ Wout, const float* __restrict__ bout,
    const float* __restrict__ vec,  float* __restrict__ dst, int lb, int tid)
{
    int j = lb * 256 + tid;
    if (j < 1024) {
        int l = j >> 5, jj = j & 31;
        float acc = bh ? bh[j] : 0.f;
        #pragma unroll
        for (int k = 0; k < 32; ++k)
            acc = fmaf(vec[l*32 + k], Wh[l*1024 + k*32 + jj], acc);
        dst[j] = acc;
    } else if (j < 1024 + 16) {
        int jj = j - 1024;
        float acc = bout ? bout[jj] : 0.f;
        #pragma unroll
        for (int k = 0; k < 32; ++k)
            acc = fmaf(vec[1024 + k], Wout[k*16 + jj], acc);
        dst[j] = acc;
    }
}

// blocks: ne 67 | ed 67 | pe 70 | pv 69 | de 67 | 4 folds x 5
__global__ __launch_bounds__(256) void prep_kernel(
    const float* ne_Win, const float* ne_Wh, const float* ne_Wout,
    const float* ed_Win, const float* ed_Wh, const float* ed_Wout,
    const float* pe_Win, const float* pe_Wh, const float* pe_Wout,
    const float* pe_lng, const float* pe_lnb, const float* pe_bh, const float* pe_bout,
    const float* pv_Win, const float* pv_Wh, const float* pv_Wout,
    const float* pv_lng, const float* pv_lnb, const float* pv_bh, const float* pv_bout,
    const float* de_Win, const float* de_Wh, const float* de_Wout,
    u32* Wne, u32* Wed, u32* Wpe, u32* Wpv, u32* Wde,
    float* Fpe, float* Fpv)
{
    int bx = blockIdx.x, tid = threadIdx.x;
    if      (bx < 67)  pack_body32(ne_Win, ne_Wh, ne_Wout, nullptr, Wne,  7, 16, 1, bx,       tid);
    else if (bx < 134) pack_body32(ed_Win, ed_Wh, ed_Wout, nullptr, Wed,  5, 16, 1, bx - 67,  tid);
    else if (bx < 204) pack_body32(pe_Win, pe_Wh, pe_Wout, pe_lng,  Wpe, 49, 16, 4, bx - 134, tid);
    else if (bx < 273) pack_body32(pv_Win, pv_Wh, pv_Wout, pv_lng,  Wpv, 33, 16, 3, bx - 204, tid);
    else if (bx < 340) pack_body32(de_Win, de_Wh, de_Wout, nullptr, Wde, 16,  3, 1, bx - 273, tid);
    else if (bx < 345) fold_body(pe_Wh, pe_bh, pe_Wout, pe_bout, pe_lnb, Fpe,        bx - 340, tid);
    else if (bx < 350) fold_body(pe_Wh, nullptr, pe_Wout, nullptr, pe_lng, Fpe+1040, bx - 345, tid);
    else if (bx < 355) fold_body(pv_Wh, pv_bh, pv_Wout, pv_bout, pv_lnb, Fpv,        bx - 350, tid);
    else               fold_body(pv_Wh, nullptr, pv_Wout, nullptr, pv_lng, Fpv+1040, bx - 355, tid);
}

__device__ __forceinline__ bf16x8 stage_chunk(const float* __restrict__ arr,
                                              size_t e, int h)
{
    const int off = h*4;
    float4 a = *(const float4*)(arr + e*16 + off);
    float4 b = *(const float4*)(arr + e*16 + off + 8);
    U4 c;
    c.u.x = pk2(a.x, a.y); c.u.y = pk2(a.z, a.w);
    c.u.z = pk2(b.x, b.y); c.u.w = pk2(b.z, b.w);
    return c.h;
}

__device__ __forceinline__ void store_relu(float* __restrict__ dst, size_t e,
                                           int h, f32x16 O)
{
    float4 s1, s2;
    s1.x = fmaxf(O[0], 0.f); s1.y = fmaxf(O[1], 0.f);
    s1.z = fmaxf(O[2], 0.f); s1.w = fmaxf(O[3], 0.f);
    s2.x = fmaxf(O[4], 0.f); s2.y = fmaxf(O[5], 0.f);
    s2.z = fmaxf(O[6], 0.f); s2.w = fmaxf(O[7], 0.f);
    *(float4*)(dst + e*16 + h*4)     = s1;
    *(float4*)(dst + e*16 + h*4 + 8) = s2;
}

#define WAVE_SETUP \
    const int lane = threadIdx.x & 63; \
    const int wid  = threadIdx.x >> 6; \
    const int el = lane & 31, h = lane >> 5;

// ---------------------------------------------------------------------------
// encode: round-1 verbatim. 512 blocks x 512 thr, 2 blocks/CU.
// ---------------------------------------------------------------------------
__global__ __launch_bounds__(512, 4) void encode_kernel(
    const float* __restrict__ nodes, const float* __restrict__ edges,
    const float* __restrict__ gvec,
    const int* __restrict__ senders, const int* __restrict__ receivers,
    const u32* __restrict__ Wne, const float* __restrict__ ne_bin,
    const float* __restrict__ ne_bh, const float* __restrict__ ne_bout,
    const u32* __restrict__ Wed, const float* __restrict__ ed_bin,
    const float* __restrict__ ed_bh, const float* __restrict__ ed_bout,
    float* __restrict__ ve, float* __restrict__ ee)
{
    __shared__ __align__(64) u32 SL[17152 + 1088];
    u32* WL = SL;
    float* WB = (float*)(SL + 17152);
    WAVE_SETUP
    const bool edge_stage = blockIdx.x >= 256;
    stage_weights32(WL, WB,
                    edge_stage ? Wed : Wne,
                    edge_stage ? ed_bin : ne_bin,
                    edge_stage ? ed_bh : ne_bh,
                    edge_stage ? ed_bout : ne_bout,
                    17152, 16, threadIdx.x, 512);
    const int lb = edge_stage ? (blockIdx.x - 256) : blockIdx.x;
    const int e = (lb*8 + wid)*32 + el;
    const int b = e >> 15;
    bf16x8 a0;
    {
        uint4 w; w.x = 0u; w.y = 0u; w.z = 0u; w.w = 0u;
        if (!edge_stage) {
            if (h == 0) {
                float2 v01 = *(const float2*)(nodes + (size_t)e*6);
                float2 v23 = *(const float2*)(nodes + (size_t)e*6 + 2);
                w.x = pk2(v01.x, v01.y); w.y = pk2(v23.x, v23.y);
            } else {
                float2 v45 = *(const float2*)(nodes + (size_t)e*6 + 4);
                w.x = pk2(v45.x, v45.y); w.y = pk2(gvec[b], 0.f);
            }
        } else {
            int s = senders[e], r = receivers[e];
            const float* ps = nodes + ((size_t)b*NN + s)*6;
            const float* pr = nodes + ((size_t)b*NN + r)*6;
            float2 s01 = *(const float2*)ps; float s2v = ps[2];
            float2 r01 = *(const float2*)pr; float r2v = pr[2];
            float r0 = s01.x - r01.x, r1 = s01.y - r01.y, r2 = s2v - r2v;
            if (h == 0) {
                w.x = pk2(edges[e], r0); w.y = pk2(r1, r2);
            } else {
                w.x = pk2(sqrtf(r0*r0 + r1*r1 + r2*r2), 0.f);
            }
        }
        U4 c; c.u = w; a0 = c.h;
    }
    float* dst = edge_stage ? ee : ve;
    f32x16 O = mlp32<1, false>(&a0, WL, WB, lane, h);
    store_relu(dst, (size_t)e, h, O);
}

// ---------------------------------------------------------------------------
// edge_update: 512-thr blocks (8 waves), 256 blocks, 1 block/CU.
// LDS: WL 17920 + WBln 2144 + X 8*544 = 24416 dw = 97.7 KB.
// ---------------------------------------------------------------------------
__global__ __launch_bounds__(512, 2) void edge_update_kernel(
    const float* __restrict__ gvec,
    const int* __restrict__ senders, const int* __restrict__ receivers,
    const float* __restrict__ ve, float* __restrict__ ee, float* __restrict__ agg,
    const u32* __restrict__ Wp, const float* __restrict__ bin,
    const float* __restrict__ F)
{
    __shared__ __align__(64) u32 SL[17920 + 2144 + 8*544];
    u32* WL = SL;
    float* WB = (float*)(SL + 17920);
    WAVE_SETUP
    float* X = (float*)(SL + 20064) + wid*544;
    stage_weights32_ln(WL, WB, Wp, bin, F, 17920, threadIdx.x, 512);
    const int e0 = (blockIdx.x*8 + wid)*32;
    const int e  = e0 + el;
    const int b  = e >> 15;
    const int s  = senders[e], r_ = receivers[e];
    bf16x8 a[4];
    a[0] = stage_chunk(ee, (size_t)e, h);
    a[1] = stage_chunk(ve, (size_t)b*NN + s, h);
    a[2] = stage_chunk(ve, (size_t)b*NN + r_, h);
    {
        uint4 w; w.x = (h == 0) ? pk2(gvec[b], 0.f) : 0u;
        w.y = 0u; w.z = 0u; w.w = 0u;
        U4 c; c.u = w; a[3] = c.h;
    }
    f32x16 O = mlp32_ln<4>(a, WL, WB, lane, h);
    float4 s1, s2;
    s1.x = fmaxf(O[0], 0.f); s1.y = fmaxf(O[1], 0.f);
    s1.z = fmaxf(O[2], 0.f); s1.w = fmaxf(O[3], 0.f);
    s2.x = fmaxf(O[4], 0.f); s2.y = fmaxf(O[5], 0.f);
    s2.z = fmaxf(O[6], 0.f); s2.w = fmaxf(O[7], 0.f);
    *(float4*)(ee + (size_t)e*16 + h*4)     = s1;
    *(float4*)(ee + (size_t)e*16 + h*4 + 8) = s2;
    // Transpose through wave-private LDS so each atomic instruction hits 4
    // receiver lines (16 lanes share a receiver).
    *(float4*)(X + el*17 + h*4)     = s1;
    *(float4*)(X + el*17 + h*4 + 8) = s2;
    const int feat = lane & 15;
    #pragma unroll
    for (int rr = 0; rr < 8; ++rr) {
        int m = (lane >> 4)*8 + rr;
        float v = X[m*17 + feat];
        int rc = __shfl(r_, m);                // lane m (h=0) holds receivers
        int eg = e0 + m;
        atomicAdd(agg + ((size_t)(eg >> 15)*NN + rc)*16 + feat, v);
    }
}

// ---------------------------------------------------------------------------
// node_update: 512-thr blocks (8 waves), 256 blocks, 1 block/CU.
// DEC: decode weights staged upfront (LDS 152 KB total).
// ---------------------------------------------------------------------------
template<bool DEC>
__global__ __launch_bounds__(512, 2) void node_update_kernel(
    const float* __restrict__ gvec,
    const float* __restrict__ agg, float* __restrict__ ve,
    const u32* __restrict__ Wp, const float* __restrict__ bin,
    const float* __restrict__ F,
    const u32* __restrict__ Wde, const float* __restrict__ de_bin,
    const float* __restrict__ de_bh, const float* __restrict__ de_bout,
    float* __restrict__ out)
{
    __shared__ __align__(64) u32 SL[DEC ? (19808 + 17152 + 1088) : 19808];
    u32* WL = SL;
    float* WB = (float*)(SL + 17664);
    u32* WL2 = SL + 19808;
    float* WB2 = (float*)(SL + 19808 + 17152);
    WAVE_SETUP
    stage_weights32_ln(WL, WB, Wp, bin, F, 17664, threadIdx.x, 512);
    if (DEC)
        stage_weights32(WL2, WB2, Wde, de_bin, de_bh, de_bout, 17152, 3,
                        threadIdx.x, 512);
    const int e = (blockIdx.x*8 + wid)*32 + el;
    const int b = e >> 15;
    bf16x8 a[3];
    a[0] = stage_chunk(agg, (size_t)e, h);
    a[1] = stage_chunk(ve,  (size_t)e, h);
    {
        uint4 w; w.x = (h == 0) ? pk2(gvec[b], 0.f) : 0u;
        w.y = 0u; w.z = 0u; w.w = 0u;
        U4 c; c.u = w; a[2] = c.h;
    }
    f32x16 O = mlp32_ln<3>(a, WL, WB, lane, h);
    if (!DEC) {
        store_relu(ve, (size_t)e, h, O);
    } else {
        bf16x8 D0, D1;
        transform32<false>(O, D0, D1);   // relu + pack
        f32x16 O2 = mlp32<1, false>(&D0, WL2, WB2, lane, h);
        if (h == 0) {
            out[(size_t)e*3 + 0] = fmaxf(O2[0], 0.f);
            out[(size_t)e*3 + 1] = fmaxf(O2[1], 0.f);
            out[(size_t)e*3 + 2] = fmaxf(O2[2], 0.f);
        }
    }
}

// ---------------------------------------------------------------------------
// launch
// ---------------------------------------------------------------------------
extern "C" void kernel_launch(void* const* d_in, const int* in_sizes, int n_in,
                              void* d_out, int out_size, void* d_ws, size_t ws_size,
                              hipStream_t stream)
{
    const float* nodes     = (const float*)d_in[0];
    const float* edges     = (const float*)d_in[1];
    const float* gvec      = (const float*)d_in[2];
    const int*   senders   = (const int*)  d_in[3];
    const int*   receivers = (const int*)  d_in[4];

    const float* ne_Win  = (const float*)d_in[5];
    const float* ne_bin  = (const float*)d_in[6];
    const float* ne_Wh   = (const float*)d_in[7];
    const float* ne_bh   = (const float*)d_in[8];
    const float* ne_Wout = (const float*)d_in[9];
    const float* ne_bout = (const float*)d_in[10];

    const float* ed_Win  = (const float*)d_in[11];
    const float* ed_bin  = (const float*)d_in[12];
    const float* ed_Wh   = (const float*)d_in[13];
    const float* ed_bh   = (const float*)d_in[14];
    const float* ed_Wout = (const float*)d_in[15];
    const float* ed_bout = (const float*)d_in[16];

    const float* pe_Win  = (const float*)d_in[17];
    const float* pe_bin  = (const float*)d_in[18];
    const float* pe_Wh   = (const float*)d_in[19];
    const float* pe_bh   = (const float*)d_in[20];
    const float* pe_Wout = (const float*)d_in[21];
    const float* pe_bout = (const float*)d_in[22];
    const float* pe_lng  = (const float*)d_in[23];
    const float* pe_lnb  = (const float*)d_in[24];

    const float* pv_Win  = (const float*)d_in[25];
    const float* pv_bin  = (const float*)d_in[26];
    const float* pv_Wh   = (const float*)d_in[27];
    const float* pv_bh   = (const float*)d_in[28];
    const float* pv_Wout = (const float*)d_in[29];
    const float* pv_bout = (const float*)d_in[30];
    const float* pv_lng  = (const float*)d_in[31];
    const float* pv_lnb  = (const float*)d_in[32];

    const float* de_Win  = (const float*)d_in[33];
    const float* de_bin  = (const float*)d_in[34];
    const float* de_Wh   = (const float*)d_in[35];
    const float* de_bh   = (const float*)d_in[36];
    const float* de_Wout = (const float*)d_in[37];
    const float* de_bout = (const float*)d_in[38];

    // workspace: ve | ee | agg0 | agg1 (4 MB each) | packed weights | folds
    float* ve   = (float*)d_ws;
    float* ee   = ve   + (size_t)1048576;
    float* agg0 = ee   + (size_t)1048576;
    float* agg1 = agg0 + (size_t)1048576;
    u32* Wne = (u32*)(agg1 + (size_t)1048576);
    u32* Wed = Wne + 17152;
    u32* Wpe = Wed + 17152;
    u32* Wpv = Wpe + 17920;
    u32* Wde = Wpv + 17664;
    float* Fpe = (float*)(Wde + 17152);   // 2080 floats
    float* Fpv = Fpe + 2080;              // 2080 floats

    prep_kernel<<<360, dim3(256), 0, stream>>>(
        ne_Win, ne_Wh, ne_Wout,
        ed_Win, ed_Wh, ed_Wout,
        pe_Win, pe_Wh, pe_Wout, pe_lng, pe_lnb, pe_bh, pe_bout,
        pv_Win, pv_Wh, pv_Wout, pv_lng, pv_lnb, pv_bh, pv_bout,
        de_Win, de_Wh, de_Wout,
        Wne, Wed, Wpe, Wpv, Wde, Fpe, Fpv);

    // zero both agg ping-pong buffers in one shot
    hipMemsetAsync(agg0, 0, (size_t)2 * 1048576 * sizeof(float), stream);

    encode_kernel<<<512, dim3(512), 0, stream>>>(nodes, edges, gvec, senders, receivers,
        Wne, ne_bin, ne_bh, ne_bout,
        Wed, ed_bin, ed_bh, ed_bout, ve, ee);

    // step 0
    edge_update_kernel<<<256, dim3(512), 0, stream>>>(gvec, senders, receivers,
        ve, ee, agg0, Wpe, pe_bin, Fpe);
    node_update_kernel<false><<<256, dim3(512), 0, stream>>>(gvec, agg0, ve,
        Wpv, pv_bin, Fpv, Wde, de_bin, de_bh, de_bout, (float*)d_out);
    // step 1 (+ fused decode)
    edge_update_kernel<<<256, dim3(512), 0, stream>>>(gvec, senders, receivers,
        ve, ee, agg1, Wpe, pe_bin, Fpe);
    node_update_kernel<true><<<256, dim3(512), 0, stream>>>(gvec, agg1, ve,
        Wpv, pv_bin, Fpv, Wde, de_bin, de_bh, de_bout, (float*)d_out);
}

// Round 6
// 237.479 us; speedup vs baseline: 1.7910x; 1.0280x over previous
//
#include <hip/hip_runtime.h>

#define BB 2
#define NN 32768
#define EN 32768

typedef unsigned int u32;
typedef __attribute__((ext_vector_type(8)))  short bf16x8;
typedef __attribute__((ext_vector_type(2)))  float f32x2;
typedef __attribute__((ext_vector_type(16))) float f32x16;

union U4 { uint4 u; bf16x8 h; };

// Single-instruction bf16 pack (no gfx950 builtin; RNE).
__device__ __forceinline__ u32 pk2(float lo, float hi) {
    u32 r;
    asm("v_cvt_pk_bf16_f32 %0, %1, %2" : "=v"(r) : "v"(lo), "v"(hi));
    return r;
}

// lane<->lane^32 sum via permlane32_swap (VALU, no LDS latency).
__device__ __forceinline__ float xor32_sum(float x) {
    float y = x;
    asm("v_permlane32_swap_b32 %0, %1" : "+v"(x), "+v"(y));
    return x + y;
}

__device__ __forceinline__ f32x16 MF32(bf16x8 a, bf16x8 b, f32x16 c) {
    return __builtin_amdgcn_mfma_f32_32x32x16_bf16(a, b, c, 0, 0, 0);
}

// ---------------------------------------------------------------------------
// 32x32 MFMA engine (round-1 proven, frozen). Lane (e = lane&31, h = lane>>5).
// C/D: col = e, row(r,h) = (r&3) + 8*(r>>2) + 4h.
// pi: f(t,h,j) = 16t + 4h + (j&3) + 8*(j>>2) -> layer-to-layer pure registers.
// ---------------------------------------------------------------------------
template<bool LN>
__device__ __forceinline__ void transform32(f32x16 D, bf16x8& B0, bf16x8& B1)
{
    f32x2 p0 = {D[0],D[1]},  p1 = {D[2],D[3]},  p2 = {D[4],D[5]},  p3 = {D[6],D[7]};
    f32x2 p4 = {D[8],D[9]},  p5 = {D[10],D[11]},p6 = {D[12],D[13]},p7 = {D[14],D[15]};
    const f32x2 zz = {0.f, 0.f};
    p0 = __builtin_elementwise_max(p0, zz); p1 = __builtin_elementwise_max(p1, zz);
    p2 = __builtin_elementwise_max(p2, zz); p3 = __builtin_elementwise_max(p3, zz);
    p4 = __builtin_elementwise_max(p4, zz); p5 = __builtin_elementwise_max(p5, zz);
    p6 = __builtin_elementwise_max(p6, zz); p7 = __builtin_elementwise_max(p7, zz);
    if (LN) {
        f32x2 sv = ((p0+p1)+(p2+p3)) + ((p4+p5)+(p6+p7));
        f32x2 ta = __builtin_elementwise_fma(p0,p0,
                   __builtin_elementwise_fma(p1,p1,
                   __builtin_elementwise_fma(p2,p2, p3*p3)));
        f32x2 tb = __builtin_elementwise_fma(p4,p4,
                   __builtin_elementwise_fma(p5,p5,
                   __builtin_elementwise_fma(p6,p6, p7*p7)));
        f32x2 tv = ta + tb;
        float s = xor32_sum(sv.x + sv.y);
        float t = xor32_sum(tv.x + tv.y);
        float mu  = s * (1.f/32.f);
        float var = fmaf(-mu, mu, t * (1.f/32.f));
        float rs  = rsqrtf(var + 1e-5f);
        float nt  = -mu * rs;
        f32x2 rs2 = {rs, rs}, nt2 = {nt, nt};
        p0 = __builtin_elementwise_fma(p0, rs2, nt2);
        p1 = __builtin_elementwise_fma(p1, rs2, nt2);
        p2 = __builtin_elementwise_fma(p2, rs2, nt2);
        p3 = __builtin_elementwise_fma(p3, rs2, nt2);
        p4 = __builtin_elementwise_fma(p4, rs2, nt2);
        p5 = __builtin_elementwise_fma(p5, rs2, nt2);
        p6 = __builtin_elementwise_fma(p6, rs2, nt2);
        p7 = __builtin_elementwise_fma(p7, rs2, nt2);
    }
    U4 c;
    c.u.x = pk2(p0.x,p0.y); c.u.y = pk2(p1.x,p1.y);
    c.u.z = pk2(p2.x,p2.y); c.u.w = pk2(p3.x,p3.y);
    B0 = c.h;
    c.u.x = pk2(p4.x,p4.y); c.u.y = pk2(p5.x,p5.y);
    c.u.z = pk2(p6.x,p6.y); c.u.w = pk2(p7.x,p7.y);
    B1 = c.h;
}

// Direct aligned f32x16 LDS load (WB 64B-aligned; h*16 floats = 64B).
__device__ __forceinline__ f32x16 load_biasC(const float* WB, int base, int h) {
    return *(const f32x16*)(WB + base + h*16);
}

// WL (dwords): [Bin NT*256][Bh 32*512][Bo 512]
template<int NT, bool LN>
__device__ __forceinline__ f32x16 mlp32(const bf16x8* bIn,
    const u32* WL, const float* WB, int lane, int h)
{
    constexpr int HB = NT*256;
    constexpr int BO = HB + 16384;
    U4 c;
    f32x16 D = load_biasC(WB, 0, h);
    #pragma unroll
    for (int t = 0; t < NT; ++t) {
        c.u = *(const uint4*)(WL + t*256 + lane*4);
        D = MF32(c.h, bIn[t], D);
    }
    c.u = *(const uint4*)(WL + HB + lane*4);        bf16x8 w0 = c.h;
    c.u = *(const uint4*)(WL + HB + 256 + lane*4);  bf16x8 w1 = c.h;
    c.u = *(const uint4*)(WL + HB + 512 + lane*4);  bf16x8 x0 = c.h;
    c.u = *(const uint4*)(WL + HB + 768 + lane*4);  bf16x8 x1 = c.h;
    f32x16 pb = load_biasC(WB, 32, h);
    bf16x8 B0, B1;
    transform32<LN>(D, B0, B1);
    #pragma unroll 4
    for (int l = 0; l < 32; ++l) {
        const int lp = (l+2 < 32) ? l+2 : 31;
        c.u = *(const uint4*)(WL + HB + lp*512 + lane*4);       bf16x8 nw0 = c.h;
        c.u = *(const uint4*)(WL + HB + lp*512 + 256 + lane*4); bf16x8 nw1 = c.h;
        const int lb_ = (l+1 < 32) ? l+1 : 31;
        f32x16 nb = load_biasC(WB, 32 + lb_*32, h);
        f32x16 E = MF32(w0, B0, pb);
        E = MF32(w1, B1, E);
        transform32<LN>(E, B0, B1);
        w0 = x0; w1 = x1; x0 = nw0; x1 = nw1; pb = nb;
    }
    c.u = *(const uint4*)(WL + BO + lane*4);        bf16x8 o0 = c.h;
    c.u = *(const uint4*)(WL + BO + 256 + lane*4);  bf16x8 o1 = c.h;
    f32x16 Co = load_biasC(WB, 1056, h);
    f32x16 O = MF32(o0, B0, Co);
    O = MF32(o1, B1, O);
    return O;
}

// ---------------------------------------------------------------------------
// Staging. DMA linear; biases permuted to the C-operand layout.
// ---------------------------------------------------------------------------
__device__ __forceinline__ void stage_dma(u32* WL, const u32* __restrict__ Wp,
                                          int wtot, int tid, int nthr)
{
    const int lane = tid & 63;
    const int step = (nthr >> 6) * 256;
    for (int C = (tid >> 6)*256; C < wtot; C += step)
        __builtin_amdgcn_global_load_lds(
            (const __attribute__((address_space(1))) u32*)(Wp + C + lane*4),
            (__attribute__((address_space(3))) u32*)(WL + C), 16, 0, 0);
}

// WB (floats): [0..32) bin | [32..1056) hidden | [1056..1088) out
__device__ __forceinline__ void stage_bias(float* WB,
    const float* __restrict__ bin, const float* __restrict__ bhid,
    const float* __restrict__ bo, int nbo, int tid, int nthr)
{
    for (int i = tid; i < 1088; i += nthr) {
        float v;
        if (i < 32) {
            int w = i, hh = w>>4, r = w&15;
            int f = (r&3) + 8*(r>>2) + 4*hh;
            v = bin[f];
        } else if (i < 1056) {
            int l = (i-32)>>5, w = (i-32)&31, hh = w>>4, r = w&15;
            int f = (r&3) + 8*(r>>2) + 4*hh;
            v = bhid[l*32 + f];
        } else {
            int w = i-1056, hh = w>>4, r = w&15;
            int f = (r&3) + 8*(r>>2) + 4*hh;
            v = (f < nbo) ? bo[f] : 0.f;
        }
        WB[i] = v;
    }
}

__device__ __forceinline__ void stage_weights32(
    u32* WL, float* WB, const u32* __restrict__ Wp,
    const float* __restrict__ bin, const float* __restrict__ bhid,
    const float* __restrict__ bo, int wtot, int nbo, int tid, int nthr)
{
    stage_dma(WL, Wp, wtot, tid, nthr);
    stage_bias(WB, bin, bhid, bo, nbo, tid, nthr);
    __syncthreads();
}

// ---------------------------------------------------------------------------
// prep: weight packing to 32x32 pi layout + LN folds + per-batch g-fold bias.
// ---------------------------------------------------------------------------
__device__ __forceinline__ void pack_body32(
    const float* __restrict__ Win, const float* __restrict__ Wh,
    const float* __restrict__ Wout, const float* __restrict__ lng,
    u32* __restrict__ dst, int din, int dout, int NT, int lb, int tid)
{
    int t = lb * 256 + tid;
    int binW = NT * 256;
    int tot = binW + 16384 + 512;
    if (t >= tot) return;
    float lo, hi;
    if (t < binW) {
        int tt = t>>8, rem = t&255, ln_ = rem>>2, d = rem&3;
        int hh = ln_>>5, m = ln_&31;
        int f0 = 16*tt + 4*hh + 2*(d&1) + 8*(d>>1);
        lo = (f0   < din) ? Win[f0*32 + m]     : 0.f;
        hi = (f0+1 < din) ? Win[(f0+1)*32 + m] : 0.f;
    } else if (t < binW + 16384) {
        int u = t - binW, l = u>>9, v = u&511;
        int tt = v>>8, rem = v&255, ln_ = rem>>2, d = rem&3;
        int hh = ln_>>5, m = ln_&31;
        int f0 = 16*tt + 4*hh + 2*(d&1) + 8*(d>>1);
        lo = Wh[l*1024 + f0*32 + m];
        hi = Wh[l*1024 + (f0+1)*32 + m];
        if (lng) { lo *= lng[l*32 + f0]; hi *= lng[l*32 + f0 + 1]; }
    } else {
        int u = t - binW - 16384;
        int tt = u>>8, rem = u&255, ln_ = rem>>2, d = rem&3;
        int hh = ln_>>5, m = ln_&31;
        int f0 = 16*tt + 4*hh + 2*(d&1) + 8*(d>>1);
        lo = (m < dout) ? Wout[f0*dout + m]     : 0.f;
        hi = (m < dout) ? Wout[(f0+1)*dout + m] : 0.f;
        if (lng) { lo *= lng[1024 + f0]; hi *= lng[1024 + f0 + 1]; }
    }
    dst[t] = pk2(lo, hi);
}

__device__ __forceinline__ void fold_body(
    const float* __restrict__ Wh,   const float* __restrict__ bh,
    const float* __restrict__ Wout, const float* __restrict__ bout,
    const float* __restrict__ lnb,  float* __restrict__ fb, int lb, int tid)
{
    int j = lb * 256 + tid;
    if (j < 1024) {
        int l = j >> 5, jj = j & 31;
        float acc = bh[j];
        #pragma unroll
        for (int k = 0; k < 32; ++k)
            acc = fmaf(lnb[l*32 + k], Wh[l*1024 + k*32 + jj], acc);
        fb[j] = acc;
    } else if (j < 1024 + 16) {
        int jj = j - 1024;
        float acc = bout[jj];
        #pragma unroll
        for (int k = 0; k < 32; ++k)
            acc = fmaf(lnb[1024 + k], Wout[k*16 + jj], acc);
        fb[j] = acc;
    }
}

// blocks: ne 67 | ed 67 | pe 69 | pv 68 | de 67 | fold pe 5 | fold pv 5 | g 1
__global__ __launch_bounds__(256) void prep_kernel(
    const float* ne_Win, const float* ne_Wh, const float* ne_Wout,
    const float* ed_Win, const float* ed_Wh, const float* ed_Wout,
    const float* pe_Win, const float* pe_Wh, const float* pe_Wout,
    const float* pe_lng, const float* pe_lnb, const float* pe_bh, const float* pe_bout,
    const float* pe_bin,
    const float* pv_Win, const float* pv_Wh, const float* pv_Wout,
    const float* pv_lng, const float* pv_lnb, const float* pv_bh, const float* pv_bout,
    const float* pv_bin,
    const float* de_Win, const float* de_Wh, const float* de_Wout,
    const float* gvec,
    u32* Wne, u32* Wed, u32* Wpe, u32* Wpv, u32* Wde,
    float* Fpe, float* Fpv)
{
    int bx = blockIdx.x, tid = threadIdx.x;
    if      (bx < 67)  pack_body32(ne_Win, ne_Wh, ne_Wout, nullptr, Wne,  7, 16, 1, bx,       tid);
    else if (bx < 134) pack_body32(ed_Win, ed_Wh, ed_Wout, nullptr, Wed,  5, 16, 1, bx - 67,  tid);
    else if (bx < 203) pack_body32(pe_Win, pe_Wh, pe_Wout, pe_lng,  Wpe, 48, 16, 3, bx - 134, tid);
    else if (bx < 271) pack_body32(pv_Win, pv_Wh, pv_Wout, pv_lng,  Wpv, 32, 16, 2, bx - 203, tid);
    else if (bx < 338) pack_body32(de_Win, de_Wh, de_Wout, nullptr, Wde, 16,  3, 1, bx - 271, tid);
    else if (bx < 343) fold_body(pe_Wh, pe_bh, pe_Wout, pe_bout, pe_lnb, Fpe, bx - 338, tid);
    else if (bx < 348) fold_body(pv_Wh, pv_bh, pv_Wout, pv_bout, pv_lnb, Fpv, bx - 343, tid);
    else {
        // per-batch layer-0 bias with the g-feature folded in (f32, exact):
        // pe: g is feature 48; pv: g is feature 32.
        if (tid < 64) {
            int b = tid >> 5, f = tid & 31;
            Fpe[1040 + tid] = pe_bin[f] + gvec[b] * pe_Win[48*32 + f];
        } else if (tid < 128) {
            int u = tid - 64, b = u >> 5, f = u & 31;
            Fpv[1040 + u] = pv_bin[f] + gvec[b] * pv_Win[32*32 + f];
        }
    }
}

// f32 source chunk -> B-frag (used for agg only; ve/ee are stored bf16 now)
__device__ __forceinline__ bf16x8 stage_chunk(const float* __restrict__ arr,
                                              size_t e, int h)
{
    const int off = h*4;
    float4 a = *(const float4*)(arr + e*16 + off);
    float4 b = *(const float4*)(arr + e*16 + off + 8);
    U4 c;
    c.u.x = pk2(a.x, a.y); c.u.y = pk2(a.z, a.w);
    c.u.z = pk2(b.x, b.y); c.u.w = pk2(b.z, b.w);
    return c.h;
}

#define WAVE_SETUP \
    const int lane = threadIdx.x & 63; \
    const int wid  = threadIdx.x >> 6; \
    const int el = lane & 31, h = lane >> 5;

// ---------------------------------------------------------------------------
// encode: 512 blocks x 512 thr, 2 blocks/CU. Outputs ve/ee as bf16
// (numerically identical to f32 store + consumer pk2).
// ---------------------------------------------------------------------------
__global__ __launch_bounds__(512, 4) void encode_kernel(
    const float* __restrict__ nodes, const float* __restrict__ edges,
    const float* __restrict__ gvec,
    const int* __restrict__ senders, const int* __restrict__ receivers,
    const u32* __restrict__ Wne, const float* __restrict__ ne_bin,
    const float* __restrict__ ne_bh, const float* __restrict__ ne_bout,
    const u32* __restrict__ Wed, const float* __restrict__ ed_bin,
    const float* __restrict__ ed_bh, const float* __restrict__ ed_bout,
    u32* __restrict__ veB, u32* __restrict__ eeB)
{
    __shared__ __align__(64) u32 SL[17152 + 1088];
    u32* WL = SL;
    float* WB = (float*)(SL + 17152);
    WAVE_SETUP
    const bool edge_stage = blockIdx.x >= 256;
    stage_weights32(WL, WB,
                    edge_stage ? Wed : Wne,
                    edge_stage ? ed_bin : ne_bin,
                    edge_stage ? ed_bh : ne_bh,
                    edge_stage ? ed_bout : ne_bout,
                    17152, 16, threadIdx.x, 512);
    const int lb = edge_stage ? (blockIdx.x - 256) : blockIdx.x;
    const int e = (lb*8 + wid)*32 + el;
    const int b = e >> 15;
    bf16x8 a0;
    {
        uint4 w; w.x = 0u; w.y = 0u; w.z = 0u; w.w = 0u;
        if (!edge_stage) {
            if (h == 0) {
                float2 v01 = *(const float2*)(nodes + (size_t)e*6);
                float2 v23 = *(const float2*)(nodes + (size_t)e*6 + 2);
                w.x = pk2(v01.x, v01.y); w.y = pk2(v23.x, v23.y);
            } else {
                float2 v45 = *(const float2*)(nodes + (size_t)e*6 + 4);
                w.x = pk2(v45.x, v45.y); w.y = pk2(gvec[b], 0.f);
            }
        } else {
            int s = senders[e], r = receivers[e];
            const float* ps = nodes + ((size_t)b*NN + s)*6;
            const float* pr = nodes + ((size_t)b*NN + r)*6;
            float2 s01 = *(const float2*)ps; float s2v = ps[2];
            float2 r01 = *(const float2*)pr; float r2v = pr[2];
            float r0 = s01.x - r01.x, r1 = s01.y - r01.y, r2 = s2v - r2v;
            if (h == 0) {
                w.x = pk2(edges[e], r0); w.y = pk2(r1, r2);
            } else {
                w.x = pk2(sqrtf(r0*r0 + r1*r1 + r2*r2), 0.f);
            }
        }
        U4 c; c.u = w; a0 = c.h;
    }
    u32* dstB = edge_stage ? eeB : veB;
    f32x16 O = mlp32<1, false>(&a0, WL, WB, lane, h);
    U4 cc;
    cc.u.x = pk2(fmaxf(O[0],0.f), fmaxf(O[1],0.f));
    cc.u.y = pk2(fmaxf(O[2],0.f), fmaxf(O[3],0.f));
    cc.u.z = pk2(fmaxf(O[4],0.f), fmaxf(O[5],0.f));
    cc.u.w = pk2(fmaxf(O[6],0.f), fmaxf(O[7],0.f));
    *(uint4*)(dstB + (size_t)e*8 + h*4) = cc.u;
}

// ---------------------------------------------------------------------------
// edge_update: 256 blocks x 512 thr, 1 block/CU. NT=3 (g folded into bias).
// bf16 in (ee, ve gathers = half the random-gather bytes), bf16 out (ee).
// ---------------------------------------------------------------------------
__global__ __launch_bounds__(512, 2) void edge_update_kernel(
    const int* __restrict__ senders, const int* __restrict__ receivers,
    const u32* __restrict__ veB, u32* __restrict__ eeB, float* __restrict__ agg,
    const u32* __restrict__ Wp, const float* __restrict__ F)
{
    __shared__ __align__(64) u32 SL[17664 + 1088 + 8*544];
    u32* WL = SL;
    float* WB = (float*)(SL + 17664);
    WAVE_SETUP
    float* X = (float*)(SL + 18752) + wid*544;
    const float* binSel = F + 1040 + ((blockIdx.x & 128) ? 32 : 0);
    stage_weights32(WL, WB, Wp, binSel, F, F + 1024, 17664, 16, threadIdx.x, 512);
    const int e0 = (blockIdx.x*8 + wid)*32;
    const int e  = e0 + el;
    const int b  = e >> 15;
    const int s  = senders[e], r_ = receivers[e];
    bf16x8 a[3];
    U4 c;
    c.u = *(const uint4*)(eeB + (size_t)e*8 + h*4);               a[0] = c.h;
    c.u = *(const uint4*)(veB + ((size_t)b*NN + s )*8 + h*4);     a[1] = c.h;
    c.u = *(const uint4*)(veB + ((size_t)b*NN + r_)*8 + h*4);     a[2] = c.h;
    f32x16 O = mlp32<3, true>(a, WL, WB, lane, h);
    float4 s1, s2;
    s1.x = fmaxf(O[0], 0.f); s1.y = fmaxf(O[1], 0.f);
    s1.z = fmaxf(O[2], 0.f); s1.w = fmaxf(O[3], 0.f);
    s2.x = fmaxf(O[4], 0.f); s2.y = fmaxf(O[5], 0.f);
    s2.z = fmaxf(O[6], 0.f); s2.w = fmaxf(O[7], 0.f);
    U4 cc;
    cc.u.x = pk2(s1.x, s1.y); cc.u.y = pk2(s1.z, s1.w);
    cc.u.z = pk2(s2.x, s2.y); cc.u.w = pk2(s2.z, s2.w);
    *(uint4*)(eeB + (size_t)e*8 + h*4) = cc.u;
    // Transpose through wave-private LDS so each atomic instruction hits 4
    // receiver lines (16 lanes share a receiver). Atomics stay f32.
    *(float4*)(X + el*17 + h*4)     = s1;
    *(float4*)(X + el*17 + h*4 + 8) = s2;
    const int feat = lane & 15;
    #pragma unroll
    for (int rr = 0; rr < 8; ++rr) {
        int m = (lane >> 4)*8 + rr;
        float v = X[m*17 + feat];
        int rc = __shfl(r_, m);                // lane m (h=0) holds receivers
        int eg = e0 + m;
        atomicAdd(agg + ((size_t)(eg >> 15)*NN + rc)*16 + feat, v);
    }
}

// ---------------------------------------------------------------------------
// node_update: 256 blocks x 512 thr, 1 block/CU. NT=2 (g folded into bias).
// agg stays f32 (atomic target); ve is bf16. DEC: decode staged upfront.
// ---------------------------------------------------------------------------
template<bool DEC>
__global__ __launch_bounds__(512, 2) void node_update_kernel(
    const float* __restrict__ agg, u32* __restrict__ veB,
    const u32* __restrict__ Wp, const float* __restrict__ F,
    const u32* __restrict__ Wde, const float* __restrict__ de_bin,
    const float* __restrict__ de_bh, const float* __restrict__ de_bout,
    float* __restrict__ out)
{
    __shared__ __align__(64) u32 SL[DEC ? (17408 + 17152 + 1088 + 1088) : (17408 + 1088)];
    u32* WL = SL;
    u32* WL2 = SL + 17408;
    float* WB  = (float*)(SL + (DEC ? 34560 : 17408));
    float* WB2 = (float*)(SL + 35648);
    WAVE_SETUP
    const float* binSel = F + 1040 + ((blockIdx.x & 128) ? 32 : 0);
    stage_weights32(WL, WB, Wp, binSel, F, F + 1024, 17408, 16, threadIdx.x, 512);
    if (DEC)
        stage_weights32(WL2, WB2, Wde, de_bin, de_bh, de_bout, 17152, 3,
                        threadIdx.x, 512);
    const int e = (blockIdx.x*8 + wid)*32 + el;
    const int b = e >> 15;
    bf16x8 a[2];
    a[0] = stage_chunk(agg, (size_t)e, h);
    {
        U4 c;
        c.u = *(const uint4*)(veB + (size_t)e*8 + h*4);
        a[1] = c.h;
    }
    f32x16 O = mlp32<2, true>(a, WL, WB, lane, h);
    if (!DEC) {
        U4 cc;
        cc.u.x = pk2(fmaxf(O[0],0.f), fmaxf(O[1],0.f));
        cc.u.y = pk2(fmaxf(O[2],0.f), fmaxf(O[3],0.f));
        cc.u.z = pk2(fmaxf(O[4],0.f), fmaxf(O[5],0.f));
        cc.u.w = pk2(fmaxf(O[6],0.f), fmaxf(O[7],0.f));
        *(uint4*)(veB + (size_t)e*8 + h*4) = cc.u;
    } else {
        bf16x8 D0, D1;
        transform32<false>(O, D0, D1);   // relu + pack
        f32x16 O2 = mlp32<1, false>(&D0, WL2, WB2, lane, h);
        if (h == 0) {
            out[(size_t)e*3 + 0] = fmaxf(O2[0], 0.f);
            out[(size_t)e*3 + 1] = fmaxf(O2[1], 0.f);
            out[(size_t)e*3 + 2] = fmaxf(O2[2], 0.f);
        }
    }
}

// ---------------------------------------------------------------------------
// launch
// ---------------------------------------------------------------------------
extern "C" void kernel_launch(void* const* d_in, const int* in_sizes, int n_in,
                              void* d_out, int out_size, void* d_ws, size_t ws_size,
                              hipStream_t stream)
{
    const float* nodes     = (const float*)d_in[0];
    const float* edges     = (const float*)d_in[1];
    const float* gvec      = (const float*)d_in[2];
    const int*   senders   = (const int*)  d_in[3];
    const int*   receivers = (const int*)  d_in[4];

    const float* ne_Win  = (const float*)d_in[5];
    const float* ne_bin  = (const float*)d_in[6];
    const float* ne_Wh   = (const float*)d_in[7];
    const float* ne_bh   = (const float*)d_in[8];
    const float* ne_Wout = (const float*)d_in[9];
    const float* ne_bout = (const float*)d_in[10];

    const float* ed_Win  = (const float*)d_in[11];
    const float* ed_bin  = (const float*)d_in[12];
    const float* ed_Wh   = (const float*)d_in[13];
    const float* ed_bh   = (const float*)d_in[14];
    const float* ed_Wout = (const float*)d_in[15];
    const float* ed_bout = (const float*)d_in[16];

    const float* pe_Win  = (const float*)d_in[17];
    const float* pe_bin  = (const float*)d_in[18];
    const float* pe_Wh   = (const float*)d_in[19];
    const float* pe_bh   = (const float*)d_in[20];
    const float* pe_Wout = (const float*)d_in[21];
    const float* pe_bout = (const float*)d_in[22];
    const float* pe_lng  = (const float*)d_in[23];
    const float* pe_lnb  = (const float*)d_in[24];

    const float* pv_Win  = (const float*)d_in[25];
    const float* pv_bin  = (const float*)d_in[26];
    const float* pv_Wh   = (const float*)d_in[27];
    const float* pv_bh   = (const float*)d_in[28];
    const float* pv_Wout = (const float*)d_in[29];
    const float* pv_bout = (const float*)d_in[30];
    const float* pv_lng  = (const float*)d_in[31];
    const float* pv_lnb  = (const float*)d_in[32];

    const float* de_Win  = (const float*)d_in[33];
    const float* de_bin  = (const float*)d_in[34];
    const float* de_Wh   = (const float*)d_in[35];
    const float* de_bh   = (const float*)d_in[36];
    const float* de_Wout = (const float*)d_in[37];
    const float* de_bout = (const float*)d_in[38];

    // workspace: ve | ee (bf16, regions kept at 4MB spacing) | agg0 | agg1 |
    //            packed weights | folds
    float* ve   = (float*)d_ws;
    float* ee   = ve   + (size_t)1048576;
    float* agg0 = ee   + (size_t)1048576;
    float* agg1 = agg0 + (size_t)1048576;
    u32* veB = (u32*)ve;
    u32* eeB = (u32*)ee;
    u32* Wne = (u32*)(agg1 + (size_t)1048576);
    u32* Wed = Wne + 17152;
    u32* Wpe = Wed + 17152;
    u32* Wpv = Wpe + 17664;
    u32* Wde = Wpv + 17408;
    float* Fpe = (float*)(Wde + 17152);   // 1104 floats
    float* Fpv = Fpe + 1104;              // 1104 floats

    prep_kernel<<<349, dim3(256), 0, stream>>>(
        ne_Win, ne_Wh, ne_Wout,
        ed_Win, ed_Wh, ed_Wout,
        pe_Win, pe_Wh, pe_Wout, pe_lng, pe_lnb, pe_bh, pe_bout, pe_bin,
        pv_Win, pv_Wh, pv_Wout, pv_lng, pv_lnb, pv_bh, pv_bout, pv_bin,
        de_Win, de_Wh, de_Wout, gvec,
        Wne, Wed, Wpe, Wpv, Wde, Fpe, Fpv);

    // zero both agg ping-pong buffers in one shot
    hipMemsetAsync(agg0, 0, (size_t)2 * 1048576 * sizeof(float), stream);

    encode_kernel<<<512, dim3(512), 0, stream>>>(nodes, edges, gvec, senders, receivers,
        Wne, ne_bin, ne_bh, ne_bout,
        Wed, ed_bin, ed_bh, ed_bout, veB, eeB);

    // step 0
    edge_update_kernel<<<256, dim3(512), 0, stream>>>(senders, receivers,
        veB, eeB, agg0, Wpe, Fpe);
    node_update_kernel<false><<<256, dim3(512), 0, stream>>>(agg0, veB,
        Wpv, Fpv, Wde, de_bin, de_bh, de_bout, (float*)d_out);
    // step 1 (+ fused decode)
    edge_update_kernel<<<256, dim3(512), 0, stream>>>(senders, receivers,
        veB, eeB, agg1, Wpe, Fpe);
    node_update_kernel<true><<<256, dim3(512), 0, stream>>>(agg1, veB,
        Wpv, Fpv, Wde, de_bin, de_bh, de_bout, (float*)d_out);
}

// Round 7
// 231.570 us; speedup vs baseline: 1.8367x; 1.0255x over previous
//
#include <hip/hip_runtime.h>

#define BB 2
#define NN 32768
#define EN 32768

typedef unsigned int u32;
typedef __attribute__((ext_vector_type(8)))  short bf16x8;
typedef __attribute__((ext_vector_type(2)))  float f32x2;
typedef __attribute__((ext_vector_type(16))) float f32x16;

union U4 { uint4 u; bf16x8 h; };

// Single-instruction bf16 pack (no gfx950 builtin; RNE).
__device__ __forceinline__ u32 pk2(float lo, float hi) {
    u32 r;
    asm("v_cvt_pk_bf16_f32 %0, %1, %2" : "=v"(r) : "v"(lo), "v"(hi));
    return r;
}

// lane<->lane^32 sum via permlane32_swap (VALU, no LDS latency).
__device__ __forceinline__ float xor32_sum(float x) {
    float y = x;
    asm("v_permlane32_swap_b32 %0, %1" : "+v"(x), "+v"(y));
    return x + y;
}

__device__ __forceinline__ f32x16 MF32(bf16x8 a, bf16x8 b, f32x16 c) {
    return __builtin_amdgcn_mfma_f32_32x32x16_bf16(a, b, c, 0, 0, 0);
}

// ---------------------------------------------------------------------------
// 32x32 MFMA engine (round-1 proven, frozen). Lane (e = lane&31, h = lane>>5).
// C/D: col = e, row(r,h) = (r&3) + 8*(r>>2) + 4h.
// pi: f(t,h,j) = 16t + 4h + (j&3) + 8*(j>>2) -> layer-to-layer pure registers.
// ---------------------------------------------------------------------------
template<bool LN>
__device__ __forceinline__ void transform32(f32x16 D, bf16x8& B0, bf16x8& B1)
{
    f32x2 p0 = {D[0],D[1]},  p1 = {D[2],D[3]},  p2 = {D[4],D[5]},  p3 = {D[6],D[7]};
    f32x2 p4 = {D[8],D[9]},  p5 = {D[10],D[11]},p6 = {D[12],D[13]},p7 = {D[14],D[15]};
    const f32x2 zz = {0.f, 0.f};
    p0 = __builtin_elementwise_max(p0, zz); p1 = __builtin_elementwise_max(p1, zz);
    p2 = __builtin_elementwise_max(p2, zz); p3 = __builtin_elementwise_max(p3, zz);
    p4 = __builtin_elementwise_max(p4, zz); p5 = __builtin_elementwise_max(p5, zz);
    p6 = __builtin_elementwise_max(p6, zz); p7 = __builtin_elementwise_max(p7, zz);
    if (LN) {
        f32x2 sv = ((p0+p1)+(p2+p3)) + ((p4+p5)+(p6+p7));
        f32x2 ta = __builtin_elementwise_fma(p0,p0,
                   __builtin_elementwise_fma(p1,p1,
                   __builtin_elementwise_fma(p2,p2, p3*p3)));
        f32x2 tb = __builtin_elementwise_fma(p4,p4,
                   __builtin_elementwise_fma(p5,p5,
                   __builtin_elementwise_fma(p6,p6, p7*p7)));
        f32x2 tv = ta + tb;
        float s = xor32_sum(sv.x + sv.y);
        float t = xor32_sum(tv.x + tv.y);
        float mu  = s * (1.f/32.f);
        float var = fmaf(-mu, mu, t * (1.f/32.f));
        float rs  = rsqrtf(var + 1e-5f);
        float nt  = -mu * rs;
        f32x2 rs2 = {rs, rs}, nt2 = {nt, nt};
        p0 = __builtin_elementwise_fma(p0, rs2, nt2);
        p1 = __builtin_elementwise_fma(p1, rs2, nt2);
        p2 = __builtin_elementwise_fma(p2, rs2, nt2);
        p3 = __builtin_elementwise_fma(p3, rs2, nt2);
        p4 = __builtin_elementwise_fma(p4, rs2, nt2);
        p5 = __builtin_elementwise_fma(p5, rs2, nt2);
        p6 = __builtin_elementwise_fma(p6, rs2, nt2);
        p7 = __builtin_elementwise_fma(p7, rs2, nt2);
    }
    U4 c;
    c.u.x = pk2(p0.x,p0.y); c.u.y = pk2(p1.x,p1.y);
    c.u.z = pk2(p2.x,p2.y); c.u.w = pk2(p3.x,p3.y);
    B0 = c.h;
    c.u.x = pk2(p4.x,p4.y); c.u.y = pk2(p5.x,p5.y);
    c.u.z = pk2(p6.x,p6.y); c.u.w = pk2(p7.x,p7.y);
    B1 = c.h;
}

// Direct aligned f32x16 LDS load (WB 64B-aligned; h*16 floats = 64B).
__device__ __forceinline__ f32x16 load_biasC(const float* WB, int base, int h) {
    return *(const f32x16*)(WB + base + h*16);
}

// WL (dwords): [Bin NT*256][Bh 32*512][Bo 512]
// unroll 8: amortize loop control, let the scheduler strength-reduce LDS
// addressing and overlap adjacent layers' glue. setprio(1) brackets the MFMA
// pair (T5: favors the matrix-feed wave in this latency-bound 2-wave regime).
template<int NT, bool LN>
__device__ __forceinline__ f32x16 mlp32(const bf16x8* bIn,
    const u32* WL, const float* WB, int lane, int h)
{
    constexpr int HB = NT*256;
    constexpr int BO = HB + 16384;
    U4 c;
    f32x16 D = load_biasC(WB, 0, h);
    #pragma unroll
    for (int t = 0; t < NT; ++t) {
        c.u = *(const uint4*)(WL + t*256 + lane*4);
        D = MF32(c.h, bIn[t], D);
    }
    c.u = *(const uint4*)(WL + HB + lane*4);        bf16x8 w0 = c.h;
    c.u = *(const uint4*)(WL + HB + 256 + lane*4);  bf16x8 w1 = c.h;
    c.u = *(const uint4*)(WL + HB + 512 + lane*4);  bf16x8 x0 = c.h;
    c.u = *(const uint4*)(WL + HB + 768 + lane*4);  bf16x8 x1 = c.h;
    f32x16 pb = load_biasC(WB, 32, h);
    bf16x8 B0, B1;
    transform32<LN>(D, B0, B1);
    #pragma unroll 8
    for (int l = 0; l < 32; ++l) {
        const int lp = (l+2 < 32) ? l+2 : 31;
        c.u = *(const uint4*)(WL + HB + lp*512 + lane*4);       bf16x8 nw0 = c.h;
        c.u = *(const uint4*)(WL + HB + lp*512 + 256 + lane*4); bf16x8 nw1 = c.h;
        const int lb_ = (l+1 < 32) ? l+1 : 31;
        f32x16 nb = load_biasC(WB, 32 + lb_*32, h);
        __builtin_amdgcn_s_setprio(1);
        f32x16 E = MF32(w0, B0, pb);
        E = MF32(w1, B1, E);
        __builtin_amdgcn_s_setprio(0);
        transform32<LN>(E, B0, B1);
        w0 = x0; w1 = x1; x0 = nw0; x1 = nw1; pb = nb;
    }
    c.u = *(const uint4*)(WL + BO + lane*4);        bf16x8 o0 = c.h;
    c.u = *(const uint4*)(WL + BO + 256 + lane*4);  bf16x8 o1 = c.h;
    f32x16 Co = load_biasC(WB, 1056, h);
    __builtin_amdgcn_s_setprio(1);
    f32x16 O = MF32(o0, B0, Co);
    O = MF32(o1, B1, O);
    __builtin_amdgcn_s_setprio(0);
    return O;
}

// ---------------------------------------------------------------------------
// Staging. DMA linear; biases permuted to the C-operand layout.
// ---------------------------------------------------------------------------
__device__ __forceinline__ void stage_dma(u32* WL, const u32* __restrict__ Wp,
                                          int wtot, int tid, int nthr)
{
    const int lane = tid & 63;
    const int step = (nthr >> 6) * 256;
    for (int C = (tid >> 6)*256; C < wtot; C += step)
        __builtin_amdgcn_global_load_lds(
            (const __attribute__((address_space(1))) u32*)(Wp + C + lane*4),
            (__attribute__((address_space(3))) u32*)(WL + C), 16, 0, 0);
}

// WB (floats): [0..32) bin | [32..1056) hidden | [1056..1088) out
__device__ __forceinline__ void stage_bias(float* WB,
    const float* __restrict__ bin, const float* __restrict__ bhid,
    const float* __restrict__ bo, int nbo, int tid, int nthr)
{
    for (int i = tid; i < 1088; i += nthr) {
        float v;
        if (i < 32) {
            int w = i, hh = w>>4, r = w&15;
            int f = (r&3) + 8*(r>>2) + 4*hh;
            v = bin[f];
        } else if (i < 1056) {
            int l = (i-32)>>5, w = (i-32)&31, hh = w>>4, r = w&15;
            int f = (r&3) + 8*(r>>2) + 4*hh;
            v = bhid[l*32 + f];
        } else {
            int w = i-1056, hh = w>>4, r = w&15;
            int f = (r&3) + 8*(r>>2) + 4*hh;
            v = (f < nbo) ? bo[f] : 0.f;
        }
        WB[i] = v;
    }
}

__device__ __forceinline__ void stage_weights32(
    u32* WL, float* WB, const u32* __restrict__ Wp,
    const float* __restrict__ bin, const float* __restrict__ bhid,
    const float* __restrict__ bo, int wtot, int nbo, int tid, int nthr)
{
    stage_dma(WL, Wp, wtot, tid, nthr);
    stage_bias(WB, bin, bhid, bo, nbo, tid, nthr);
    __syncthreads();
}

// ---------------------------------------------------------------------------
// prep: weight packing to 32x32 pi layout + LN folds + per-batch g-fold bias.
// ---------------------------------------------------------------------------
__device__ __forceinline__ void pack_body32(
    const float* __restrict__ Win, const float* __restrict__ Wh,
    const float* __restrict__ Wout, const float* __restrict__ lng,
    u32* __restrict__ dst, int din, int dout, int NT, int lb, int tid)
{
    int t = lb * 256 + tid;
    int binW = NT * 256;
    int tot = binW + 16384 + 512;
    if (t >= tot) return;
    float lo, hi;
    if (t < binW) {
        int tt = t>>8, rem = t&255, ln_ = rem>>2, d = rem&3;
        int hh = ln_>>5, m = ln_&31;
        int f0 = 16*tt + 4*hh + 2*(d&1) + 8*(d>>1);
        lo = (f0   < din) ? Win[f0*32 + m]     : 0.f;
        hi = (f0+1 < din) ? Win[(f0+1)*32 + m] : 0.f;
    } else if (t < binW + 16384) {
        int u = t - binW, l = u>>9, v = u&511;
        int tt = v>>8, rem = v&255, ln_ = rem>>2, d = rem&3;
        int hh = ln_>>5, m = ln_&31;
        int f0 = 16*tt + 4*hh + 2*(d&1) + 8*(d>>1);
        lo = Wh[l*1024 + f0*32 + m];
        hi = Wh[l*1024 + (f0+1)*32 + m];
        if (lng) { lo *= lng[l*32 + f0]; hi *= lng[l*32 + f0 + 1]; }
    } else {
        int u = t - binW - 16384;
        int tt = u>>8, rem = u&255, ln_ = rem>>2, d = rem&3;
        int hh = ln_>>5, m = ln_&31;
        int f0 = 16*tt + 4*hh + 2*(d&1) + 8*(d>>1);
        lo = (m < dout) ? Wout[f0*dout + m]     : 0.f;
        hi = (m < dout) ? Wout[(f0+1)*dout + m] : 0.f;
        if (lng) { lo *= lng[1024 + f0]; hi *= lng[1024 + f0 + 1]; }
    }
    dst[t] = pk2(lo, hi);
}

__device__ __forceinline__ void fold_body(
    const float* __restrict__ Wh,   const float* __restrict__ bh,
    const float* __restrict__ Wout, const float* __restrict__ bout,
    const float* __restrict__ lnb,  float* __restrict__ fb, int lb, int tid)
{
    int j = lb * 256 + tid;
    if (j < 1024) {
        int l = j >> 5, jj = j & 31;
        float acc = bh[j];
        #pragma unroll
        for (int k = 0; k < 32; ++k)
            acc = fmaf(lnb[l*32 + k], Wh[l*1024 + k*32 + jj], acc);
        fb[j] = acc;
    } else if (j < 1024 + 16) {
        int jj = j - 1024;
        float acc = bout[jj];
        #pragma unroll
        for (int k = 0; k < 32; ++k)
            acc = fmaf(lnb[1024 + k], Wout[k*16 + jj], acc);
        fb[j] = acc;
    }
}

// blocks: ne 67 | ed 67 | pe 69 | pv 68 | de 67 | fold pe 5 | fold pv 5 | g 1
__global__ __launch_bounds__(256) void prep_kernel(
    const float* ne_Win, const float* ne_Wh, const float* ne_Wout,
    const float* ed_Win, const float* ed_Wh, const float* ed_Wout,
    const float* pe_Win, const float* pe_Wh, const float* pe_Wout,
    const float* pe_lng, const float* pe_lnb, const float* pe_bh, const float* pe_bout,
    const float* pe_bin,
    const float* pv_Win, const float* pv_Wh, const float* pv_Wout,
    const float* pv_lng, const float* pv_lnb, const float* pv_bh, const float* pv_bout,
    const float* pv_bin,
    const float* de_Win, const float* de_Wh, const float* de_Wout,
    const float* gvec,
    u32* Wne, u32* Wed, u32* Wpe, u32* Wpv, u32* Wde,
    float* Fpe, float* Fpv)
{
    int bx = blockIdx.x, tid = threadIdx.x;
    if      (bx < 67)  pack_body32(ne_Win, ne_Wh, ne_Wout, nullptr, Wne,  7, 16, 1, bx,       tid);
    else if (bx < 134) pack_body32(ed_Win, ed_Wh, ed_Wout, nullptr, Wed,  5, 16, 1, bx - 67,  tid);
    else if (bx < 203) pack_body32(pe_Win, pe_Wh, pe_Wout, pe_lng,  Wpe, 48, 16, 3, bx - 134, tid);
    else if (bx < 271) pack_body32(pv_Win, pv_Wh, pv_Wout, pv_lng,  Wpv, 32, 16, 2, bx - 203, tid);
    else if (bx < 338) pack_body32(de_Win, de_Wh, de_Wout, nullptr, Wde, 16,  3, 1, bx - 271, tid);
    else if (bx < 343) fold_body(pe_Wh, pe_bh, pe_Wout, pe_bout, pe_lnb, Fpe, bx - 338, tid);
    else if (bx < 348) fold_body(pv_Wh, pv_bh, pv_Wout, pv_bout, pv_lnb, Fpv, bx - 343, tid);
    else {
        // per-batch layer-0 bias with the g-feature folded in (f32, exact):
        // pe: g is feature 48; pv: g is feature 32.
        if (tid < 64) {
            int b = tid >> 5, f = tid & 31;
            Fpe[1040 + tid] = pe_bin[f] + gvec[b] * pe_Win[48*32 + f];
        } else if (tid < 128) {
            int u = tid - 64, b = u >> 5, f = u & 31;
            Fpv[1040 + u] = pv_bin[f] + gvec[b] * pv_Win[32*32 + f];
        }
    }
}

// f32 source chunk -> B-frag (used for agg only; ve/ee are stored bf16 now)
__device__ __forceinline__ bf16x8 stage_chunk(const float* __restrict__ arr,
                                              size_t e, int h)
{
    const int off = h*4;
    float4 a = *(const float4*)(arr + e*16 + off);
    float4 b = *(const float4*)(arr + e*16 + off + 8);
    U4 c;
    c.u.x = pk2(a.x, a.y); c.u.y = pk2(a.z, a.w);
    c.u.z = pk2(b.x, b.y); c.u.w = pk2(b.z, b.w);
    return c.h;
}

#define WAVE_SETUP \
    const int lane = threadIdx.x & 63; \
    const int wid  = threadIdx.x >> 6; \
    const int el = lane & 31, h = lane >> 5;

// ---------------------------------------------------------------------------
// encode: 512 blocks x 512 thr, 2 blocks/CU. Outputs ve/ee as bf16
// (numerically identical to f32 store + consumer pk2).
// ---------------------------------------------------------------------------
__global__ __launch_bounds__(512, 4) void encode_kernel(
    const float* __restrict__ nodes, const float* __restrict__ edges,
    const float* __restrict__ gvec,
    const int* __restrict__ senders, const int* __restrict__ receivers,
    const u32* __restrict__ Wne, const float* __restrict__ ne_bin,
    const float* __restrict__ ne_bh, const float* __restrict__ ne_bout,
    const u32* __restrict__ Wed, const float* __restrict__ ed_bin,
    const float* __restrict__ ed_bh, const float* __restrict__ ed_bout,
    u32* __restrict__ veB, u32* __restrict__ eeB)
{
    __shared__ __align__(64) u32 SL[17152 + 1088];
    u32* WL = SL;
    float* WB = (float*)(SL + 17152);
    WAVE_SETUP
    const bool edge_stage = blockIdx.x >= 256;
    stage_weights32(WL, WB,
                    edge_stage ? Wed : Wne,
                    edge_stage ? ed_bin : ne_bin,
                    edge_stage ? ed_bh : ne_bh,
                    edge_stage ? ed_bout : ne_bout,
                    17152, 16, threadIdx.x, 512);
    const int lb = edge_stage ? (blockIdx.x - 256) : blockIdx.x;
    const int e = (lb*8 + wid)*32 + el;
    const int b = e >> 15;
    bf16x8 a0;
    {
        uint4 w; w.x = 0u; w.y = 0u; w.z = 0u; w.w = 0u;
        if (!edge_stage) {
            if (h == 0) {
                float2 v01 = *(const float2*)(nodes + (size_t)e*6);
                float2 v23 = *(const float2*)(nodes + (size_t)e*6 + 2);
                w.x = pk2(v01.x, v01.y); w.y = pk2(v23.x, v23.y);
            } else {
                float2 v45 = *(const float2*)(nodes + (size_t)e*6 + 4);
                w.x = pk2(v45.x, v45.y); w.y = pk2(gvec[b], 0.f);
            }
        } else {
            int s = senders[e], r = receivers[e];
            const float* ps = nodes + ((size_t)b*NN + s)*6;
            const float* pr = nodes + ((size_t)b*NN + r)*6;
            float2 s01 = *(const float2*)ps; float s2v = ps[2];
            float2 r01 = *(const float2*)pr; float r2v = pr[2];
            float r0 = s01.x - r01.x, r1 = s01.y - r01.y, r2 = s2v - r2v;
            if (h == 0) {
                w.x = pk2(edges[e], r0); w.y = pk2(r1, r2);
            } else {
                w.x = pk2(sqrtf(r0*r0 + r1*r1 + r2*r2), 0.f);
            }
        }
        U4 c; c.u = w; a0 = c.h;
    }
    u32* dstB = edge_stage ? eeB : veB;
    f32x16 O = mlp32<1, false>(&a0, WL, WB, lane, h);
    U4 cc;
    cc.u.x = pk2(fmaxf(O[0],0.f), fmaxf(O[1],0.f));
    cc.u.y = pk2(fmaxf(O[2],0.f), fmaxf(O[3],0.f));
    cc.u.z = pk2(fmaxf(O[4],0.f), fmaxf(O[5],0.f));
    cc.u.w = pk2(fmaxf(O[6],0.f), fmaxf(O[7],0.f));
    *(uint4*)(dstB + (size_t)e*8 + h*4) = cc.u;
}

// ---------------------------------------------------------------------------
// edge_update: 256 blocks x 512 thr, 1 block/CU. NT=3 (g folded into bias).
// bf16 in (ee, ve gathers = half the random-gather bytes), bf16 out (ee).
// ---------------------------------------------------------------------------
__global__ __launch_bounds__(512, 2) void edge_update_kernel(
    const int* __restrict__ senders, const int* __restrict__ receivers,
    const u32* __restrict__ veB, u32* __restrict__ eeB, float* __restrict__ agg,
    const u32* __restrict__ Wp, const float* __restrict__ F)
{
    __shared__ __align__(64) u32 SL[17664 + 1088 + 8*544];
    u32* WL = SL;
    float* WB = (float*)(SL + 17664);
    WAVE_SETUP
    float* X = (float*)(SL + 18752) + wid*544;
    const float* binSel = F + 1040 + ((blockIdx.x & 128) ? 32 : 0);
    stage_weights32(WL, WB, Wp, binSel, F, F + 1024, 17664, 16, threadIdx.x, 512);
    const int e0 = (blockIdx.x*8 + wid)*32;
    const int e  = e0 + el;
    const int b  = e >> 15;
    const int s  = senders[e], r_ = receivers[e];
    bf16x8 a[3];
    U4 c;
    c.u = *(const uint4*)(eeB + (size_t)e*8 + h*4);               a[0] = c.h;
    c.u = *(const uint4*)(veB + ((size_t)b*NN + s )*8 + h*4);     a[1] = c.h;
    c.u = *(const uint4*)(veB + ((size_t)b*NN + r_)*8 + h*4);     a[2] = c.h;
    f32x16 O = mlp32<3, true>(a, WL, WB, lane, h);
    float4 s1, s2;
    s1.x = fmaxf(O[0], 0.f); s1.y = fmaxf(O[1], 0.f);
    s1.z = fmaxf(O[2], 0.f); s1.w = fmaxf(O[3], 0.f);
    s2.x = fmaxf(O[4], 0.f); s2.y = fmaxf(O[5], 0.f);
    s2.z = fmaxf(O[6], 0.f); s2.w = fmaxf(O[7], 0.f);
    U4 cc;
    cc.u.x = pk2(s1.x, s1.y); cc.u.y = pk2(s1.z, s1.w);
    cc.u.z = pk2(s2.x, s2.y); cc.u.w = pk2(s2.z, s2.w);
    *(uint4*)(eeB + (size_t)e*8 + h*4) = cc.u;
    // Transpose through wave-private LDS so each atomic instruction hits 4
    // receiver lines (16 lanes share a receiver). Atomics stay f32.
    *(float4*)(X + el*17 + h*4)     = s1;
    *(float4*)(X + el*17 + h*4 + 8) = s2;
    const int feat = lane & 15;
    #pragma unroll
    for (int rr = 0; rr < 8; ++rr) {
        int m = (lane >> 4)*8 + rr;
        float v = X[m*17 + feat];
        int rc = __shfl(r_, m);                // lane m (h=0) holds receivers
        int eg = e0 + m;
        atomicAdd(agg + ((size_t)(eg >> 15)*NN + rc)*16 + feat, v);
    }
}

// ---------------------------------------------------------------------------
// node_update: 256 blocks x 512 thr, 1 block/CU. NT=2 (g folded into bias).
// agg stays f32 (atomic target); ve is bf16. DEC: decode staged upfront.
// ---------------------------------------------------------------------------
template<bool DEC>
__global__ __launch_bounds__(512, 2) void node_update_kernel(
    const float* __restrict__ agg, u32* __restrict__ veB,
    const u32* __restrict__ Wp, const float* __restrict__ F,
    const u32* __restrict__ Wde, const float* __restrict__ de_bin,
    const float* __restrict__ de_bh, const float* __restrict__ de_bout,
    float* __restrict__ out)
{
    __shared__ __align__(64) u32 SL[DEC ? (17408 + 17152 + 1088 + 1088) : (17408 + 1088)];
    u32* WL = SL;
    u32* WL2 = SL + 17408;
    float* WB  = (float*)(SL + (DEC ? 34560 : 17408));
    float* WB2 = (float*)(SL + 35648);
    WAVE_SETUP
    const float* binSel = F + 1040 + ((blockIdx.x & 128) ? 32 : 0);
    stage_weights32(WL, WB, Wp, binSel, F, F + 1024, 17408, 16, threadIdx.x, 512);
    if (DEC)
        stage_weights32(WL2, WB2, Wde, de_bin, de_bh, de_bout, 17152, 3,
                        threadIdx.x, 512);
    const int e = (blockIdx.x*8 + wid)*32 + el;
    const int b = e >> 15;
    bf16x8 a[2];
    a[0] = stage_chunk(agg, (size_t)e, h);
    {
        U4 c;
        c.u = *(const uint4*)(veB + (size_t)e*8 + h*4);
        a[1] = c.h;
    }
    f32x16 O = mlp32<2, true>(a, WL, WB, lane, h);
    if (!DEC) {
        U4 cc;
        cc.u.x = pk2(fmaxf(O[0],0.f), fmaxf(O[1],0.f));
        cc.u.y = pk2(fmaxf(O[2],0.f), fmaxf(O[3],0.f));
        cc.u.z = pk2(fmaxf(O[4],0.f), fmaxf(O[5],0.f));
        cc.u.w = pk2(fmaxf(O[6],0.f), fmaxf(O[7],0.f));
        *(uint4*)(veB + (size_t)e*8 + h*4) = cc.u;
    } else {
        bf16x8 D0, D1;
        transform32<false>(O, D0, D1);   // relu + pack
        f32x16 O2 = mlp32<1, false>(&D0, WL2, WB2, lane, h);
        if (h == 0) {
            out[(size_t)e*3 + 0] = fmaxf(O2[0], 0.f);
            out[(size_t)e*3 + 1] = fmaxf(O2[1], 0.f);
            out[(size_t)e*3 + 2] = fmaxf(O2[2], 0.f);
        }
    }
}

// ---------------------------------------------------------------------------
// launch
// ---------------------------------------------------------------------------
extern "C" void kernel_launch(void* const* d_in, const int* in_sizes, int n_in,
                              void* d_out, int out_size, void* d_ws, size_t ws_size,
                              hipStream_t stream)
{
    const float* nodes     = (const float*)d_in[0];
    const float* edges     = (const float*)d_in[1];
    const float* gvec      = (const float*)d_in[2];
    const int*   senders   = (const int*)  d_in[3];
    const int*   receivers = (const int*)  d_in[4];

    const float* ne_Win  = (const float*)d_in[5];
    const float* ne_bin  = (const float*)d_in[6];
    const float* ne_Wh   = (const float*)d_in[7];
    const float* ne_bh   = (const float*)d_in[8];
    const float* ne_Wout = (const float*)d_in[9];
    const float* ne_bout = (const float*)d_in[10];

    const float* ed_Win  = (const float*)d_in[11];
    const float* ed_bin  = (const float*)d_in[12];
    const float* ed_Wh   = (const float*)d_in[13];
    const float* ed_bh   = (const float*)d_in[14];
    const float* ed_Wout = (const float*)d_in[15];
    const float* ed_bout = (const float*)d_in[16];

    const float* pe_Win  = (const float*)d_in[17];
    const float* pe_bin  = (const float*)d_in[18];
    const float* pe_Wh   = (const float*)d_in[19];
    const float* pe_bh   = (const float*)d_in[20];
    const float* pe_Wout = (const float*)d_in[21];
    const float* pe_bout = (const float*)d_in[22];
    const float* pe_lng  = (const float*)d_in[23];
    const float* pe_lnb  = (const float*)d_in[24];

    const float* pv_Win  = (const float*)d_in[25];
    const float* pv_bin  = (const float*)d_in[26];
    const float* pv_Wh   = (const float*)d_in[27];
    const float* pv_bh   = (const float*)d_in[28];
    const float* pv_Wout = (const float*)d_in[29];
    const float* pv_bout = (const float*)d_in[30];
    const float* pv_lng  = (const float*)d_in[31];
    const float* pv_lnb  = (const float*)d_in[32];

    const float* de_Win  = (const float*)d_in[33];
    const float* de_bin  = (const float*)d_in[34];
    const float* de_Wh   = (const float*)d_in[35];
    const float* de_bh   = (const float*)d_in[36];
    const float* de_Wout = (const float*)d_in[37];
    const float* de_bout = (const float*)d_in[38];

    // workspace: ve | ee (bf16, regions kept at 4MB spacing) | agg0 | agg1 |
    //            packed weights | folds
    float* ve   = (float*)d_ws;
    float* ee   = ve   + (size_t)1048576;
    float* agg0 = ee   + (size_t)1048576;
    float* agg1 = agg0 + (size_t)1048576;
    u32* veB = (u32*)ve;
    u32* eeB = (u32*)ee;
    u32* Wne = (u32*)(agg1 + (size_t)1048576);
    u32* Wed = Wne + 17152;
    u32* Wpe = Wed + 17152;
    u32* Wpv = Wpe + 17664;
    u32* Wde = Wpv + 17408;
    float* Fpe = (float*)(Wde + 17152);   // 1104 floats
    float* Fpv = Fpe + 1104;              // 1104 floats

    prep_kernel<<<349, dim3(256), 0, stream>>>(
        ne_Win, ne_Wh, ne_Wout,
        ed_Win, ed_Wh, ed_Wout,
        pe_Win, pe_Wh, pe_Wout, pe_lng, pe_lnb, pe_bh, pe_bout, pe_bin,
        pv_Win, pv_Wh, pv_Wout, pv_lng, pv_lnb, pv_bh, pv_bout, pv_bin,
        de_Win, de_Wh, de_Wout, gvec,
        Wne, Wed, Wpe, Wpv, Wde, Fpe, Fpv);

    // zero both agg ping-pong buffers in one shot
    hipMemsetAsync(agg0, 0, (size_t)2 * 1048576 * sizeof(float), stream);

    encode_kernel<<<512, dim3(512), 0, stream>>>(nodes, edges, gvec, senders, receivers,
        Wne, ne_bin, ne_bh, ne_bout,
        Wed, ed_bin, ed_bh, ed_bout, veB, eeB);

    // step 0
    edge_update_kernel<<<256, dim3(512), 0, stream>>>(senders, receivers,
        veB, eeB, agg0, Wpe, Fpe);
    node_update_kernel<false><<<256, dim3(512), 0, stream>>>(agg0, veB,
        Wpv, Fpv, Wde, de_bin, de_bh, de_bout, (float*)d_out);
    // step 1 (+ fused decode)
    edge_update_kernel<<<256, dim3(512), 0, stream>>>(senders, receivers,
        veB, eeB, agg1, Wpe, Fpe);
    node_update_kernel<true><<<256, dim3(512), 0, stream>>>(agg1, veB,
        Wpv, Fpv, Wde, de_bin, de_bh, de_bout, (float*)d_out);
}